// Round 5
// baseline (256.990 us; speedup 1.0000x reference)
//
#include <hip/hip_runtime.h>
#include <math.h>

#define NIMG 8
#define NCLS 80
#define HW 40000
#define M (NCLS*HW)          // 3,200,000 per image
#define UBINS 4096           // uniform bins over s in [0,1): bin = (int)(s*4096)
#define CANDL 4096           // collect cap (fallback path)
#define SPILL_CAP 65536
#define BCAP 1024
#define TOPK 1000
#define OUTK 100
#define PRE_T 0.05f
#define NMS_T 0.6f
#define FLOOR_BITS 0x3E800000u
#define FLOOR_SAFE 0.2494f

// device-global scratch; counters re-zeroed every call, rest guarded by counts
__device__ unsigned int       g_scnt[NIMG][32];    // padded: 128B per image
__device__ unsigned int       g_ovf[NIMG];
__device__ float              g_xthr[NIMG * HW];   // 1.25 MB, L2-resident
__device__ float              g_sct[NIMG * HW];    // exact sigmoid(centerness)
__device__ unsigned long long g_key[NIMG][SPILL_CAP];

__device__ __forceinline__ float sigmoid_exact(float x){
    return 1.0f / (1.0f + expf(-x));   // bit-matches ref (absmax 0 across sessions)
}

__device__ __forceinline__ unsigned long long shfl_xor_u64(unsigned long long v, int j){
    int lo = __shfl_xor((int)(unsigned int)(v & 0xffffffffull), j);
    int hi = __shfl_xor((int)(unsigned int)(v >> 32), j);
    return ((unsigned long long)(unsigned int)hi << 32) | (unsigned long long)(unsigned int)lo;
}

// k0: zero counters; exact sct table; xthr[hw] = logit(FLOOR_SAFE/sct), +inf if >=1.
__global__ void k0_init(const float* __restrict__ cent){
    int t = blockIdx.x * blockDim.x + threadIdx.x;
    if (t < NIMG * 32) ((unsigned int*)g_scnt)[t] = 0u;
    if (t < NIMG) g_ovf[t] = 0u;
    if (t < NIMG * HW){
        float pct = sigmoid_exact(cent[t]);
        g_sct[t] = pct;
        float a = FLOOR_SAFE / pct;
        float xt;
        if (a >= 1.0f) xt = 3.0e38f;
        else {
            float am = fminf(a, 0.98f);
            xt = logf(am / (1.0f - am));
        }
        g_xthr[t] = xt;
    }
}

// k1: PROVEN form (<73 us) — byte-identical to Round 4. Do not restructure.
__global__ void __launch_bounds__(1024) k1_spill(const float* __restrict__ cls){
    const int n   = blockIdx.y;
    const int tid = threadIdx.x;
    const int e0  = blockIdx.x * 4096 + tid * 4;
    __shared__ unsigned long long skey[BCAP];
    __shared__ unsigned int lcnt, lbase;
    if (tid == 0) lcnt = 0u;
    __syncthreads();
    if (e0 < M){
        const int c  = e0 / HW;
        const int hw = e0 - c * HW;
        float4 x  = *(const float4*)(cls + (size_t)n * M + e0);
        float4 th = *(const float4*)(g_xthr + n * HW + hw);
        #define SPILL1(J, XV) \
        if (XV >= (J==0?th.x:J==1?th.y:J==2?th.z:th.w)){ \
            float p_ = sigmoid_exact(XV); \
            if (p_ > PRE_T){ \
                float s_ = p_ * g_sct[n * HW + hw + J]; \
                unsigned long long key_ = ((unsigned long long)__float_as_uint(s_) << 32) \
                    | (unsigned long long)(0xFFFFFFFFu - (unsigned int)((hw + J) * NCLS + c)); \
                unsigned int pp_ = atomicAdd(&lcnt, 1u); \
                if (pp_ < BCAP) skey[pp_] = key_; \
            } \
        }
        SPILL1(0, x.x)
        SPILL1(1, x.y)
        SPILL1(2, x.z)
        SPILL1(3, x.w)
        #undef SPILL1
    }
    __syncthreads();
    unsigned int raw = lcnt;
    unsigned int cnt = raw < BCAP ? raw : BCAP;
    if (tid == 0){
        lbase = cnt ? atomicAdd(&g_scnt[n][0], cnt) : 0u;
        if (raw > BCAP) g_ovf[n] = 1u;
    }
    __syncthreads();
    unsigned int base = lbase;
    for (unsigned int i = tid; i < cnt; i += 1024){
        unsigned int pos = base + i;
        if (pos < SPILL_CAP) g_key[n][pos] = skey[i];
    }
}

struct SelPhase {
    unsigned int hist[UBINS];                 // 16 KB
    unsigned int cs[256];                     // coarse sums -> IN-PLACE suffix sums
    unsigned int wtot[4];                     // per-wave suffix totals
    unsigned long long keysL[CANDL];          // 32 KB (collect + sort buffer)
};
struct NmsPhase {
    float ox1[TOPK], oy1[TOPK], ox2[TOPK], oy2[TOPK], oar[TOPK];  // offset boxes (fp32 as ref)
    float bxs[TOPK][4];
    float sc[TOPK];
    int   lab[TOPK];
    int   keeplist[OUTK];
    unsigned int  Wc[16][80];     // per-wave per-class counts -> column-exclusive prefixes
    unsigned int  ctot[80];       // class totals (input to parallel prefix)
    unsigned int  coff[81];       // class-exclusive prefix
    unsigned int  wcnt[16];       // keep-compaction wave counts -> prefix
    unsigned short ord[1024];     // class-bucketed candidate ranks (stable in rank)
    unsigned char validf[TOPK];
    unsigned char supp[TOPK];     // used by the serial-NMS fallback only
    unsigned char keepf[1024];
};
union KU { SelPhase sel; NmsPhase nms; };     // ~55 KB (phases don't overlap)

// Register/shfl bitonic step for j<=32 (partner in-wave). Element tid in va,
// tid+1024 in vb. Region (idx & k)==0 is descending (matches LDS convention).
// Hand-verified incl. K=1024 (vb region flips via (tid+1024)&K) and K=2048.
#define REGSTEP(K_, J_) { \
    unsigned long long pa = shfl_xor_u64(va, (J_)); \
    unsigned long long pb = shfl_xor_u64(vb, (J_)); \
    bool fa = ((tid & (J_)) == 0); \
    bool da = ((tid & (K_)) == 0); \
    bool db = (((tid + 1024) & (K_)) == 0); \
    va = (fa == da) ? (va > pa ? va : pa) : (va < pa ? va : pa); \
    vb = (fa == db) ? (vb > pb ? vb : pb) : (vb < pb ? vb : pb); \
}

// k2 (R5): deserialized. S ~ 12.8K/image (measured via R4 counters; modeA removed
// as dead code). hist -> PARALLEL cut-find (suffix scans; exact equivalent of the
// serial scan: cut = max{b: suffix(b)>=TOPK}) -> collect -> HYBRID bitonic
// (j<=32 in-register via shfl_xor, j>=64 via LDS: ~21 barriers vs 66) with
// post-sort order VERIFY -> per-class register NMS with parallel coff scan.
// Safety nets: verify-fail => re-collect + proven plain bitonic; s_flag => full
// rescan (serial, verbatim); C>2048 => O(C^2) rank.
__global__ void __launch_bounds__(1024) k2_select_nms(const float* __restrict__ cls,
                                                      const float* __restrict__ loc,
                                                      const float* __restrict__ reg,
                                                      const int*   __restrict__ imsz,
                                                      float* __restrict__ out){
    const int n = blockIdx.x;
    const int tid = threadIdx.x;
    const int lane = tid & 63;
    const int wv   = tid >> 6;
    __shared__ KU u;
    __shared__ unsigned long long stop[TOPK];
    __shared__ unsigned int lcnt, s_cut, s_flag, s_nmsfb, s_cnt, s_c, s_csn, s_Cest, s_srtbad;

    for (int i = tid; i < UBINS; i += 1024) u.sel.hist[i] = 0u;
    if (tid == 0){ s_nmsfb = 0u; s_srtbad = 0u; s_c = 0xFFFFFFFFu; s_csn = 0u;
                   s_Cest = 0u; s_cut = 0u; lcnt = 0u; }
    if (tid < TOPK) stop[tid] = 0ull;
    __syncthreads();

    unsigned int scnt_raw = g_scnt[n][0];
    unsigned int ovf_f    = g_ovf[n];
    unsigned int S = scnt_raw < SPILL_CAP ? scnt_raw : SPILL_CAP;

    // hist pass (ballot/c025 removed: c025 derived from suffix sums below)
    for (unsigned int i = tid; i < S; i += 1024){
        unsigned long long k = g_key[n][i];
        float s = __uint_as_float((unsigned int)(k >> 32));
        atomicAdd(&u.sel.hist[(int)(s * 4096.0f)], 1u);
    }
    __syncthreads();
    if (tid < 256){
        unsigned int s = 0;
        int base = tid * 16;
        #pragma unroll
        for (int i = 0; i < 16; ++i) s += u.sel.hist[base + i];
        u.sel.cs[tid] = s;
    }
    __syncthreads();
    // in-place inclusive SUFFIX scan of cs[256] (4 waves, shfl_down)
    if (tid < 256){
        unsigned int v = u.sel.cs[tid];
        #pragma unroll
        for (int d = 1; d < 64; d <<= 1){
            unsigned int t = __shfl_down(v, d);
            if (lane + d < 64) v += t;
        }
        if (lane == 0) u.sel.wtot[wv] = v;
        u.sel.cs[tid] = v;
    }
    __syncthreads();
    if (tid < 256){
        unsigned int tail = 0;
        for (int w = wv + 1; w < 4; ++w) tail += u.sel.wtot[w];
        u.sel.cs[tid] += tail;      // cs now holds global suffix sums css[t]
    }
    __syncthreads();
    // coarse crossing: c* = max{t: css[t] >= TOPK} (unique since css non-increasing)
    if (tid < 256){
        unsigned int a = u.sel.cs[tid];
        unsigned int b = (tid == 255) ? 0u : u.sel.cs[tid + 1];
        if (a >= TOPK && b < TOPK){ s_c = (unsigned int)tid; s_csn = b; }
    }
    __syncthreads();
    // fine crossing within block c* (wave 0, 16-lane suffix scan)
    if (wv == 0 && s_c != 0xFFFFFFFFu){
        unsigned int cst = s_c;
        unsigned int h = (lane < 16) ? u.sel.hist[cst * 16 + lane] : 0u;
        #pragma unroll
        for (int d = 1; d < 16; d <<= 1){
            unsigned int t = __shfl_down(h, d);
            if (lane + d < 16) h += t;
        }
        unsigned int gs  = h + s_csn;            // global suffix at bin cst*16+lane
        unsigned int gsn = __shfl_down(gs, 1);
        if (lane == 15) gsn = s_csn;
        if (lane < 16 && gs >= TOPK && gsn < TOPK){ s_cut = cst * 16 + lane; s_Cest = gs; }
    }
    __syncthreads();
    if (tid == 0){
        unsigned int c025 = u.sel.cs[64];        // suffix at bin 1024 == count{s>=0.25}
        s_flag = (scnt_raw > SPILL_CAP) || ovf_f || (s_c == 0xFFFFFFFFu) ||
                 (c025 < TOPK) || (s_Cest > CANDL) ? 1u : 0u;
    }
    __syncthreads();

    if (s_flag){
        // ---- fallback: exact full rescan (serial cut-find kept verbatim; ~never)
        for (int i = tid; i < UBINS; i += 1024) u.sel.hist[i] = 0u;
        __syncthreads();
        const float* cls_n = cls + (size_t)n * M;
        const float* sct_n = g_sct + n * HW;
        for (int e = tid; e < M; e += 1024){
            float p = sigmoid_exact(cls_n[e]);
            if (p > PRE_T){
                int c = e / HW; int hw = e - c * HW;
                float s = p * sct_n[hw];
                atomicAdd(&u.sel.hist[(int)(s * 4096.0f)], 1u);
            }
        }
        __syncthreads();
        if (tid < 256){
            unsigned int s = 0;
            int base = tid * 16;
            #pragma unroll
            for (int i = 0; i < 16; ++i) s += u.sel.hist[base + i];
            u.sel.cs[tid] = s;
        }
        __syncthreads();
        if (tid == 0){
            unsigned int acc = 0; int cut = 0; int c = 255;
            for (; c >= 0; --c){ if (acc + u.sel.cs[c] >= TOPK) break; acc += u.sel.cs[c]; }
            if (c >= 0){
                int b = c*16 + 15;
                for (;; --b){ acc += u.sel.hist[b]; if (acc >= TOPK || b == c*16) break; }
                cut = b;
            }
            while (acc > CANDL && cut < UBINS){ acc -= u.sel.hist[cut]; cut++; }
            s_cut = (unsigned int)cut;
        }
        __syncthreads();
        unsigned int cutb = s_cut;
        for (int e = tid; e < M; e += 1024){
            float p = sigmoid_exact(cls_n[e]);
            if (p > PRE_T){
                int c = e / HW; int hw = e - c * HW;
                float s = p * sct_n[hw];
                if ((int)(s * 4096.0f) >= (int)cutb){
                    unsigned int pos = atomicAdd(&lcnt, 1u);
                    if (pos < CANDL){
                        unsigned int idx = (unsigned int)(hw * NCLS + c);
                        u.sel.keysL[pos] = ((unsigned long long)__float_as_uint(s) << 32)
                                         | (unsigned long long)(0xFFFFFFFFu - idx);
                    }
                }
            }
        }
    } else {
        // ---- collect keys with bin >= cut (ballot-compacted, proven)
        unsigned int cutb = s_cut;
        for (unsigned int i = tid; i < S; i += 1024){
            unsigned long long k = g_key[n][i];
            float s = __uint_as_float((unsigned int)(k >> 32));
            bool pass = ((unsigned int)(int)(s * 4096.0f)) >= cutb;
            unsigned long long mb = __ballot(pass);
            unsigned int wcnt_ = (unsigned int)__popcll(mb);
            unsigned int base = 0;
            if (lane == 0 && wcnt_) base = atomicAdd(&lcnt, wcnt_);
            base = (unsigned int)__builtin_amdgcn_readfirstlane((int)base);
            if (pass){
                unsigned int p = base + (unsigned int)__popcll(mb & ((1ull << lane) - 1ull));
                if (p < CANDL) u.sel.keysL[p] = k;
            }
        }
    }
    __syncthreads();

    int C = (int)(lcnt < CANDL ? lcnt : CANDL);
    unsigned long long kk = 0ull;
    if (C <= 2048){
        // ---- hybrid bitonic, Nsort=2048 (zero-pad sorts last; keys unique)
        for (int i = C + tid; i < 2048; i += 1024) u.sel.keysL[i] = 0ull;
        __syncthreads();
        unsigned long long va = u.sel.keysL[tid];          // thread-private slots:
        unsigned long long vb = u.sel.keysL[tid + 1024];   // load/writeback race-free
        REGSTEP(2,1)
        REGSTEP(4,2)  REGSTEP(4,1)
        REGSTEP(8,4)  REGSTEP(8,2)  REGSTEP(8,1)
        REGSTEP(16,8) REGSTEP(16,4) REGSTEP(16,2) REGSTEP(16,1)
        REGSTEP(32,16) REGSTEP(32,8) REGSTEP(32,4) REGSTEP(32,2) REGSTEP(32,1)
        REGSTEP(64,32) REGSTEP(64,16) REGSTEP(64,8) REGSTEP(64,4) REGSTEP(64,2) REGSTEP(64,1)
        for (int k = 128; k <= 2048; k <<= 1){
            if (k == 2048){
                unsigned long long mx = va > vb ? va : vb;
                unsigned long long mn = va > vb ? vb : va;
                va = mx; vb = mn;                          // j=1024 step in-thread
            }
            u.sel.keysL[tid] = va; u.sel.keysL[tid + 1024] = vb;
            __syncthreads();
            for (int j = (k == 2048) ? 512 : (k >> 1); j >= 64; j >>= 1){
                int i  = ((tid & ~(j - 1)) << 1) | (tid & (j - 1));
                int p2 = i | j;
                unsigned long long a = u.sel.keysL[i];
                unsigned long long b = u.sel.keysL[p2];
                bool up = ((i & k) == 0);
                if (up ? (a < b) : (a > b)){ u.sel.keysL[i] = b; u.sel.keysL[p2] = a; }
                __syncthreads();
            }
            va = u.sel.keysL[tid]; vb = u.sel.keysL[tid + 1024];
            REGSTEP(k,32) REGSTEP(k,16) REGSTEP(k,8) REGSTEP(k,4) REGSTEP(k,2) REGSTEP(k,1)
        }
        u.sel.keysL[tid] = va; u.sel.keysL[tid + 1024] = vb;
        __syncthreads();
        // ---- verify descending order (covers all 2047 adjacent pairs)
        bool bad = (u.sel.keysL[tid] < u.sel.keysL[tid + 1]);
        if (tid <= 1022) bad = bad || (u.sel.keysL[tid + 1024] < u.sel.keysL[tid + 1025]);
        if (bad) atomicOr(&s_srtbad, 1u);
        __syncthreads();
        if (s_srtbad){
            // ---- safety net: re-collect (mode-appropriate) + proven plain bitonic
            if (tid == 0) lcnt = 0u;
            __syncthreads();
            unsigned int cutb = s_cut;
            if (s_flag){
                const float* cls_n = cls + (size_t)n * M;
                const float* sct_n = g_sct + n * HW;
                for (int e = tid; e < M; e += 1024){
                    float p = sigmoid_exact(cls_n[e]);
                    if (p > PRE_T){
                        int c = e / HW; int hw = e - c * HW;
                        float s = p * sct_n[hw];
                        if ((int)(s * 4096.0f) >= (int)cutb){
                            unsigned int pos = atomicAdd(&lcnt, 1u);
                            if (pos < CANDL){
                                unsigned int idx = (unsigned int)(hw * NCLS + c);
                                u.sel.keysL[pos] = ((unsigned long long)__float_as_uint(s) << 32)
                                                 | (unsigned long long)(0xFFFFFFFFu - idx);
                            }
                        }
                    }
                }
            } else {
                for (unsigned int i = tid; i < S; i += 1024){
                    unsigned long long k = g_key[n][i];
                    float s = __uint_as_float((unsigned int)(k >> 32));
                    bool pass = ((unsigned int)(int)(s * 4096.0f)) >= cutb;
                    unsigned long long mb = __ballot(pass);
                    unsigned int wcnt_ = (unsigned int)__popcll(mb);
                    unsigned int base = 0;
                    if (lane == 0 && wcnt_) base = atomicAdd(&lcnt, wcnt_);
                    base = (unsigned int)__builtin_amdgcn_readfirstlane((int)base);
                    if (pass){
                        unsigned int p = base + (unsigned int)__popcll(mb & ((1ull << lane) - 1ull));
                        if (p < CANDL) u.sel.keysL[p] = k;
                    }
                }
            }
            __syncthreads();
            int C2 = (int)(lcnt < CANDL ? lcnt : CANDL);
            for (int i = C2 + tid; i < 2048; i += 1024) u.sel.keysL[i] = 0ull;
            __syncthreads();
            for (int k = 2; k <= 2048; k <<= 1){
                for (int j = k >> 1; j > 0; j >>= 1){
                    int i  = ((tid & ~(j - 1)) << 1) | (tid & (j - 1));
                    int p2 = i | j;
                    unsigned long long a = u.sel.keysL[i];
                    unsigned long long b = u.sel.keysL[p2];
                    bool up = ((i & k) == 0);
                    if (up ? (a < b) : (a > b)){ u.sel.keysL[i] = b; u.sel.keysL[p2] = a; }
                    __syncthreads();
                }
            }
        }
        kk = (tid < TOPK) ? u.sel.keysL[tid] : 0ull;
    } else {
        // rare-shape fallback: O(C^2) rank (proven path)
        for (int i = tid; i < C; i += 1024){
            unsigned long long k = u.sel.keysL[i];
            int rank = 0;
            for (int j = 0; j < C; ++j) rank += (u.sel.keysL[j] > k) ? 1 : 0;
            if (rank < TOPK) stop[rank] = k;
        }
        __syncthreads();
        kk = (tid < TOPK) ? stop[tid] : 0ull;
    }
    __syncthreads();   // fence all sel reads before union reuse writes

    // ---- NMS phase (u.nms aliases u.sel — all sel reads are done)
    float rx1 = 0.f, ry1 = 0.f, rx2 = -1.f, ry2 = -1.f, rar = 1.f;
    float ihh = (float)imsz[2*n + 0];
    float iww = (float)imsz[2*n + 1];

    u.nms.keepf[tid] = 0;
    { unsigned int* wz = &u.nms.Wc[0][0];
      for (int i = tid; i < 16*80; i += 1024) wz[i] = 0u; }

    if (tid < TOPK){
        unsigned int bits = (unsigned int)(kk >> 32);
        float s = __uint_as_float(bits);
        u.nms.supp[tid] = 0;
        if (s > 0.0f){
            unsigned int idx = 0xFFFFFFFFu - (unsigned int)(kk & 0xFFFFFFFFull);
            int hw = (int)(idx / NCLS);
            int c  = (int)(idx % NCLS);
            int l  = c + 1;
            float x  = loc[2*hw], y = loc[2*hw + 1];
            float r0 = reg[((size_t)n*4 + 0)*HW + hw];
            float r1 = reg[((size_t)n*4 + 1)*HW + hw];
            float r2 = reg[((size_t)n*4 + 2)*HW + hw];
            float r3 = reg[((size_t)n*4 + 3)*HW + hw];
            float x1 = fminf(fmaxf(x - r0, 0.0f), iww - 1.0f);
            float y1 = fminf(fmaxf(y - r1, 0.0f), ihh - 1.0f);
            float x2 = fminf(fmaxf(x + r2, 0.0f), iww - 1.0f);
            float y2 = fminf(fmaxf(y + r3, 0.0f), ihh - 1.0f);
            u.nms.bxs[tid][0] = x1; u.nms.bxs[tid][1] = y1;
            u.nms.bxs[tid][2] = x2; u.nms.bxs[tid][3] = y2;
            float off = (float)l * 100000.0f;   // fp32, as reference (quantizes!)
            float a1 = x1 + off, b1 = y1 + off, a2 = x2 + off, b2 = y2 + off;
            float ar = (a2 - a1 + 1.0f) * (b2 - b1 + 1.0f);
            u.nms.ox1[tid] = a1; u.nms.oy1[tid] = b1;
            u.nms.ox2[tid] = a2; u.nms.oy2[tid] = b2; u.nms.oar[tid] = ar;
            rx1 = a1; ry1 = b1; rx2 = a2; ry2 = b2; rar = ar;
            u.nms.sc[tid] = s; u.nms.lab[tid] = l; u.nms.validf[tid] = 1;
        } else {
            u.nms.validf[tid] = 0; u.nms.sc[tid] = 0.0f; u.nms.lab[tid] = 0;
            u.nms.bxs[tid][0] = u.nms.bxs[tid][1] = 0.0f;
            u.nms.bxs[tid][2] = u.nms.bxs[tid][3] = 0.0f;
            u.nms.ox1[tid] = 0.f; u.nms.oy1[tid] = 0.f;
            u.nms.ox2[tid] = -1.f; u.nms.oy2[tid] = -1.f; u.nms.oar[tid] = 1.f;
        }
    }
    __syncthreads();

    // ---- class bucketing (stable in rank): counts -> column prefix -> scatter
    int mk = -1;
    if (tid < TOPK && u.nms.validf[tid]) mk = u.nms.lab[tid] - 1;
    if (mk >= 0) atomicAdd(&u.nms.Wc[wv][mk], 1u);
    __syncthreads();
    if (tid < NCLS){
        unsigned int acc = 0;
        for (int w = 0; w < 16; ++w){
            unsigned int v = u.nms.Wc[w][tid];
            u.nms.Wc[w][tid] = acc;
            acc += v;
        }
        u.nms.ctot[tid] = acc;            // class total
        if (acc > 64) atomicOr(&s_nmsfb, 1u);
    }
    __syncthreads();
    // parallel exclusive prefix over 80 class totals (wave-0 shfl scan)
    if (wv == 0){
        unsigned int v = u.nms.ctot[lane];            // classes 0..63
        unsigned int inc = v;
        #pragma unroll
        for (int d = 1; d < 64; d <<= 1){
            unsigned int t = __shfl_up(inc, d);
            if (lane >= d) inc += t;
        }
        u.nms.coff[lane + 1] = inc;                   // coff[1..64]
        if (lane == 0) u.nms.coff[0] = 0u;
        unsigned int base = __shfl(inc, 63);
        unsigned int inc2 = (lane < 16) ? u.nms.ctot[64 + lane] : 0u;
        #pragma unroll
        for (int d = 1; d < 16; d <<= 1){
            unsigned int t = __shfl_up(inc2, d);
            if (lane >= d) inc2 += t;
        }
        if (lane < 16) u.nms.coff[65 + lane] = base + inc2;   // coff[65..80]
    }
    __syncthreads();

    if (!s_nmsfb){
        // stable within-wave same-class prefix via shfl (register-only)
        int below = 0;
        for (int l = 0; l < 64; ++l){
            int ok = __shfl(mk, l);
            below += (l < lane && ok == mk) ? 1 : 0;
        }
        if (mk >= 0){
            unsigned int pos = u.nms.coff[mk] + u.nms.Wc[wv][mk] + (unsigned int)below;
            u.nms.ord[pos] = (unsigned short)tid;
        }
        __syncthreads();

        // per-class greedy NMS, all in registers (wave w owns classes w, w+16, ...)
        for (int k = wv; k < NCLS; k += 16){
            int base = (int)u.nms.coff[k];
            int ck   = (int)u.nms.coff[k + 1] - base;
            if (ck <= 0) continue;
            int rr = (lane < ck) ? (int)u.nms.ord[base + lane] : -1;
            float bx1 = 0.f, by1 = 0.f, bx2 = -1.f, by2 = -1.f, bar = 1.f;
            if (rr >= 0){
                bx1 = u.nms.ox1[rr]; by1 = u.nms.oy1[rr];
                bx2 = u.nms.ox2[rr]; by2 = u.nms.oy2[rr]; bar = u.nms.oar[rr];
            }
            int sup = 0;
            for (int p = 0; p < ck; ++p){
                int keep_p = !__shfl(sup, p);          // wave-uniform
                if (keep_p){
                    float px1 = __shfl(bx1, p), py1 = __shfl(by1, p);
                    float px2 = __shfl(bx2, p), py2 = __shfl(by2, p);
                    float par = __shfl(bar, p);
                    if (lane > p && rr >= 0){
                        float ix1 = fmaxf(px1, bx1);
                        float iy1 = fmaxf(py1, by1);
                        float ix2 = fminf(px2, bx2);
                        float iy2 = fminf(py2, by2);
                        float iw_ = fmaxf(ix2 - ix1 + 1.0f, 0.0f);
                        float ih_ = fmaxf(iy2 - iy1 + 1.0f, 0.0f);
                        float inter = iw_ * ih_;
                        float iou = inter / (par + bar - inter);
                        if (iou > NMS_T) sup = 1;
                    }
                }
            }
            if (rr >= 0) u.nms.keepf[rr] = sup ? 0 : 1;
        }
        __syncthreads();

        // compact kept candidates in global rank order -> keeplist[0..cnt)
        int kf = (int)u.nms.keepf[tid];
        unsigned long long mb = __ballot(kf != 0);
        if (lane == 0) u.nms.wcnt[wv] = (unsigned int)__popcll(mb);
        __syncthreads();
        if (wv == 0){
            unsigned int v = (lane < 16) ? u.nms.wcnt[lane] : 0u;
            unsigned int orig = v;
            for (int d = 1; d < 16; d <<= 1){
                unsigned int t = __shfl_up(v, d);
                if (lane >= d) v += t;
            }
            if (lane < 16) u.nms.wcnt[lane] = v - orig;   // exclusive
            if (lane == 15) s_cnt = (v < OUTK ? v : OUTK);
        }
        __syncthreads();
        if (kf){
            unsigned int slot = u.nms.wcnt[wv] + (unsigned int)__popcll(mb & ((1ull << lane) - 1ull));
            if (slot < OUTK) u.nms.keeplist[slot] = tid;
        }
    } else {
        // ---- fallback: original serial NMS scan (c_k > 64; ~never on this data)
        int cnt = 0;
        for (int i = 0; i < TOPK; ++i){
            bool keep_i = u.nms.validf[i] && !u.nms.supp[i];
            if (keep_i){
                if (tid == 0) u.nms.keeplist[cnt] = i;
                if (tid < TOPK && tid != i){
                    float ix1 = fmaxf(u.nms.ox1[i], rx1);
                    float iy1 = fmaxf(u.nms.oy1[i], ry1);
                    float ix2 = fminf(u.nms.ox2[i], rx2);
                    float iy2 = fminf(u.nms.oy2[i], ry2);
                    float iw_ = fmaxf(ix2 - ix1 + 1.0f, 0.0f);
                    float ih_ = fmaxf(iy2 - iy1 + 1.0f, 0.0f);
                    float inter = iw_ * ih_;
                    float iou = inter / (u.nms.oar[i] + rar - inter);
                    if (iou > NMS_T) u.nms.supp[tid] = 1;
                }
                cnt++;
                __syncthreads();
                if (cnt == OUTK) break;
            }
        }
        if (tid == 0) s_cnt = (unsigned int)(cnt < OUTK ? cnt : OUTK);
    }
    __syncthreads();

    int cnt = (int)s_cnt;
    if (tid < OUTK){
        float r0=0.f,r1=0.f,r2=0.f,r3=0.f,r4=0.f,r5=0.f;
        if (tid < cnt){
            int i = u.nms.keeplist[tid];
            r0 = u.nms.bxs[i][0]; r1 = u.nms.bxs[i][1];
            r2 = u.nms.bxs[i][2]; r3 = u.nms.bxs[i][3];
            r4 = sqrtf(u.nms.sc[i]); r5 = (float)u.nms.lab[i];
        }
        float* o = out + ((size_t)n*OUTK + tid)*6;
        o[0]=r0; o[1]=r1; o[2]=r2; o[3]=r3; o[4]=r4; o[5]=r5;
    }
}

extern "C" void kernel_launch(void* const* d_in, const int* in_sizes, int n_in,
                              void* d_out, int out_size, void* d_ws, size_t ws_size,
                              hipStream_t stream){
    const float* loc  = (const float*)d_in[0];
    const float* cls  = (const float*)d_in[1];
    const float* reg  = (const float*)d_in[2];
    const float* cent = (const float*)d_in[3];
    const int*   imsz = (const int*)d_in[4];
    float* out = (float*)d_out;

    hipLaunchKernelGGL(k0_init,       dim3(625),                 dim3(512),  0, stream, cent);
    hipLaunchKernelGGL(k1_spill,      dim3((M+4095)/4096, NIMG), dim3(1024), 0, stream, cls);
    hipLaunchKernelGGL(k2_select_nms, dim3(NIMG),                dim3(1024), 0, stream,
                       cls, loc, reg, imsz, out);
}

// Round 6
// 249.335 us; speedup vs baseline: 1.0307x; 1.0307x over previous
//
#include <hip/hip_runtime.h>
#include <math.h>

#define NIMG 8
#define NCLS 80
#define HW 40000
#define M (NCLS*HW)          // 3,200,000 per image
#define UBINS 4096           // uniform bins over s in [0,1): bin = (int)(s*4096)
#define CANDL 4096           // collect cap (fallback path)
#define SPILL_CAP 65536
#define BCAP 1024
#define TOPK 1000
#define OUTK 100
#define PRE_T 0.05f
#define NMS_T 0.6f
#define FLOOR_BITS 0x3E800000u
#define FLOOR_SAFE 0.2494f

// device-global scratch; counters re-zeroed every call, rest guarded by counts
__device__ unsigned int       g_scnt[NIMG][32];    // padded: 128B per image
__device__ unsigned int       g_ovf[NIMG];
__device__ unsigned int       g_hist[NIMG][UBINS]; // 128 KB: built by k1 (R6)
__device__ float              g_xthr[NIMG * HW];   // 1.25 MB, L2-resident
__device__ float              g_sct[NIMG * HW];    // exact sigmoid(centerness)
__device__ unsigned long long g_key[NIMG][SPILL_CAP];

__device__ __forceinline__ float sigmoid_exact(float x){
    return 1.0f / (1.0f + expf(-x));   // bit-matches ref (absmax 0 across sessions)
}

__device__ __forceinline__ unsigned long long shfl_xor_u64(unsigned long long v, int j){
    int lo = __shfl_xor((int)(unsigned int)(v & 0xffffffffull), j);
    int hi = __shfl_xor((int)(unsigned int)(v >> 32), j);
    return ((unsigned long long)(unsigned int)hi << 32) | (unsigned long long)(unsigned int)lo;
}

// k0: zero counters + g_hist; exact sct table; xthr = logit(FLOOR_SAFE/sct).
__global__ void k0_init(const float* __restrict__ cent){
    int t = blockIdx.x * blockDim.x + threadIdx.x;
    if (t < NIMG * 32) ((unsigned int*)g_scnt)[t] = 0u;
    if (t < NIMG) g_ovf[t] = 0u;
    if (t < NIMG * UBINS) ((unsigned int*)g_hist)[t] = 0u;
    if (t < NIMG * HW){
        float pct = sigmoid_exact(cent[t]);
        g_sct[t] = pct;
        float a = FLOOR_SAFE / pct;
        float xt;
        if (a >= 1.0f) xt = 3.0e38f;
        else {
            float am = fminf(a, 0.98f);
            xt = logf(am / (1.0f - am));
        }
        g_xthr[t] = xt;
    }
}

// k1: PROVEN form (<76 us) + ONE addition (R6): spilled keys also atomicAdd the
// global score histogram (~12.8K atomics over 6256 blocks — negligible; hot
// path untouched). Hist counts the UNCAPPED spill set; any mismatch vs g_key
// implies g_ovf/SPILL_CAP tripped => s_flag => full rescan (consistent).
__global__ void __launch_bounds__(1024) k1_spill(const float* __restrict__ cls){
    const int n   = blockIdx.y;
    const int tid = threadIdx.x;
    const int e0  = blockIdx.x * 4096 + tid * 4;
    __shared__ unsigned long long skey[BCAP];
    __shared__ unsigned int lcnt, lbase;
    if (tid == 0) lcnt = 0u;
    __syncthreads();
    if (e0 < M){
        const int c  = e0 / HW;
        const int hw = e0 - c * HW;
        float4 x  = *(const float4*)(cls + (size_t)n * M + e0);
        float4 th = *(const float4*)(g_xthr + n * HW + hw);
        #define SPILL1(J, XV) \
        if (XV >= (J==0?th.x:J==1?th.y:J==2?th.z:th.w)){ \
            float p_ = sigmoid_exact(XV); \
            if (p_ > PRE_T){ \
                float s_ = p_ * g_sct[n * HW + hw + J]; \
                unsigned long long key_ = ((unsigned long long)__float_as_uint(s_) << 32) \
                    | (unsigned long long)(0xFFFFFFFFu - (unsigned int)((hw + J) * NCLS + c)); \
                atomicAdd(&g_hist[n][(int)(s_ * 4096.0f)], 1u); \
                unsigned int pp_ = atomicAdd(&lcnt, 1u); \
                if (pp_ < BCAP) skey[pp_] = key_; \
            } \
        }
        SPILL1(0, x.x)
        SPILL1(1, x.y)
        SPILL1(2, x.z)
        SPILL1(3, x.w)
        #undef SPILL1
    }
    __syncthreads();
    unsigned int raw = lcnt;
    unsigned int cnt = raw < BCAP ? raw : BCAP;
    if (tid == 0){
        lbase = cnt ? atomicAdd(&g_scnt[n][0], cnt) : 0u;
        if (raw > BCAP) g_ovf[n] = 1u;
    }
    __syncthreads();
    unsigned int base = lbase;
    for (unsigned int i = tid; i < cnt; i += 1024){
        unsigned int pos = base + i;
        if (pos < SPILL_CAP) g_key[n][pos] = skey[i];
    }
}

struct SelPhase {
    unsigned int hist[UBINS];                 // 16 KB (loaded from g_hist, 4 iters)
    unsigned int cs[256];                     // coarse sums -> IN-PLACE suffix sums
    unsigned int wtot[4];                     // per-wave suffix totals
    unsigned long long keysL[CANDL];          // 32 KB (collect + sort buffer)
};
struct NmsPhase {
    float ox1[TOPK], oy1[TOPK], ox2[TOPK], oy2[TOPK], oar[TOPK];  // offset boxes (fp32 as ref)
    float bxs[TOPK][4];
    float sc[TOPK];
    int   lab[TOPK];
    int   keeplist[OUTK];
    unsigned int  Wc[16][80];     // per-wave per-class counts -> column-exclusive prefixes
    unsigned int  ctot[80];       // class totals (input to parallel prefix)
    unsigned int  coff[81];       // class-exclusive prefix
    unsigned int  wcnt[16];       // keep-compaction wave counts -> prefix
    unsigned short ord[1024];     // class-bucketed candidate ranks (stable in rank)
    unsigned char validf[TOPK];
    unsigned char supp[TOPK];     // used by the serial-NMS fallback only
    unsigned char keepf[1024];
};
union KU { SelPhase sel; NmsPhase nms; };     // ~55 KB (phases don't overlap)

// Register/shfl bitonic steps (region (idx & k)==0 descending; proven R5).
#define REGSTEP(K_, J_) { \
    unsigned long long pa = shfl_xor_u64(va, (J_)); \
    unsigned long long pb = shfl_xor_u64(vb, (J_)); \
    bool fa = ((tid & (J_)) == 0); \
    bool da = ((tid & (K_)) == 0); \
    bool db = (((tid + 1024) & (K_)) == 0); \
    va = (fa == da) ? (va > pa ? va : pa) : (va < pa ? va : pa); \
    vb = (fa == db) ? (vb > pb ? vb : pb) : (vb < pb ? vb : pb); \
}
#define REGSTEP1(K_, J_) { \
    unsigned long long pa = shfl_xor_u64(va, (J_)); \
    bool fa = ((tid & (J_)) == 0); \
    bool da = ((tid & (K_)) == 0); \
    va = (fa == da) ? (va > pa ? va : pa) : (va < pa ? va : pa); \
}

// k2 (R6): hist pass ELIMINATED (g_hist from k1; 4-iter coalesced LDS load).
// Parallel cut-find (R5 proven) -> collect -> hybrid bitonic sized to C
// (1024 when C<=1024: 1 elem/thread, 10 LDS steps; else 2048 R5 path), both
// verify-guarded with shared safety net -> per-class register NMS (R2 proven).
__global__ void __launch_bounds__(1024) k2_select_nms(const float* __restrict__ cls,
                                                      const float* __restrict__ loc,
                                                      const float* __restrict__ reg,
                                                      const int*   __restrict__ imsz,
                                                      float* __restrict__ out){
    const int n = blockIdx.x;
    const int tid = threadIdx.x;
    const int lane = tid & 63;
    const int wv   = tid >> 6;
    __shared__ KU u;
    __shared__ unsigned long long stop[TOPK];
    __shared__ unsigned int lcnt, s_cut, s_flag, s_nmsfb, s_cnt, s_c, s_csn, s_Cest, s_srtbad;

    for (int i = tid; i < UBINS; i += 1024) u.sel.hist[i] = g_hist[n][i];
    if (tid == 0){ s_nmsfb = 0u; s_srtbad = 0u; s_c = 0xFFFFFFFFu; s_csn = 0u;
                   s_Cest = 0u; s_cut = 0u; lcnt = 0u; }
    if (tid < TOPK) stop[tid] = 0ull;
    __syncthreads();

    unsigned int scnt_raw = g_scnt[n][0];
    unsigned int ovf_f    = g_ovf[n];
    unsigned int S = scnt_raw < SPILL_CAP ? scnt_raw : SPILL_CAP;

    if (tid < 256){
        unsigned int s = 0;
        int base = tid * 16;
        #pragma unroll
        for (int i = 0; i < 16; ++i) s += u.sel.hist[base + i];
        u.sel.cs[tid] = s;
    }
    __syncthreads();
    // in-place inclusive SUFFIX scan of cs[256] (4 waves, shfl_down)
    if (tid < 256){
        unsigned int v = u.sel.cs[tid];
        #pragma unroll
        for (int d = 1; d < 64; d <<= 1){
            unsigned int t = __shfl_down(v, d);
            if (lane + d < 64) v += t;
        }
        if (lane == 0) u.sel.wtot[wv] = v;
        u.sel.cs[tid] = v;
    }
    __syncthreads();
    if (tid < 256){
        unsigned int tail = 0;
        for (int w = wv + 1; w < 4; ++w) tail += u.sel.wtot[w];
        u.sel.cs[tid] += tail;      // cs now holds global suffix sums css[t]
    }
    __syncthreads();
    // coarse crossing: c* = max{t: css[t] >= TOPK}
    if (tid < 256){
        unsigned int a = u.sel.cs[tid];
        unsigned int b = (tid == 255) ? 0u : u.sel.cs[tid + 1];
        if (a >= TOPK && b < TOPK){ s_c = (unsigned int)tid; s_csn = b; }
    }
    __syncthreads();
    // fine crossing within block c* (wave 0, 16-lane suffix scan)
    if (wv == 0 && s_c != 0xFFFFFFFFu){
        unsigned int cst = s_c;
        unsigned int h = (lane < 16) ? u.sel.hist[cst * 16 + lane] : 0u;
        #pragma unroll
        for (int d = 1; d < 16; d <<= 1){
            unsigned int t = __shfl_down(h, d);
            if (lane + d < 16) h += t;
        }
        unsigned int gs  = h + s_csn;            // global suffix at bin cst*16+lane
        unsigned int gsn = __shfl_down(gs, 1);
        if (lane == 15) gsn = s_csn;
        if (lane < 16 && gs >= TOPK && gsn < TOPK){ s_cut = cst * 16 + lane; s_Cest = gs; }
    }
    __syncthreads();
    if (tid == 0){
        unsigned int c025 = u.sel.cs[64];        // suffix at bin 1024 == count{s>=0.25}
        s_flag = (scnt_raw > SPILL_CAP) || ovf_f || (s_c == 0xFFFFFFFFu) ||
                 (c025 < TOPK) || (s_Cest > CANDL) ? 1u : 0u;
    }
    __syncthreads();

    if (s_flag){
        // ---- fallback: exact full rescan (serial cut-find kept verbatim; ~never)
        for (int i = tid; i < UBINS; i += 1024) u.sel.hist[i] = 0u;
        __syncthreads();
        const float* cls_n = cls + (size_t)n * M;
        const float* sct_n = g_sct + n * HW;
        for (int e = tid; e < M; e += 1024){
            float p = sigmoid_exact(cls_n[e]);
            if (p > PRE_T){
                int c = e / HW; int hw = e - c * HW;
                float s = p * sct_n[hw];
                atomicAdd(&u.sel.hist[(int)(s * 4096.0f)], 1u);
            }
        }
        __syncthreads();
        if (tid < 256){
            unsigned int s = 0;
            int base = tid * 16;
            #pragma unroll
            for (int i = 0; i < 16; ++i) s += u.sel.hist[base + i];
            u.sel.cs[tid] = s;
        }
        __syncthreads();
        if (tid == 0){
            unsigned int acc = 0; int cut = 0; int c = 255;
            for (; c >= 0; --c){ if (acc + u.sel.cs[c] >= TOPK) break; acc += u.sel.cs[c]; }
            if (c >= 0){
                int b = c*16 + 15;
                for (;; --b){ acc += u.sel.hist[b]; if (acc >= TOPK || b == c*16) break; }
                cut = b;
            }
            while (acc > CANDL && cut < UBINS){ acc -= u.sel.hist[cut]; cut++; }
            s_cut = (unsigned int)cut;
        }
        __syncthreads();
        unsigned int cutb = s_cut;
        for (int e = tid; e < M; e += 1024){
            float p = sigmoid_exact(cls_n[e]);
            if (p > PRE_T){
                int c = e / HW; int hw = e - c * HW;
                float s = p * sct_n[hw];
                if ((int)(s * 4096.0f) >= (int)cutb){
                    unsigned int pos = atomicAdd(&lcnt, 1u);
                    if (pos < CANDL){
                        unsigned int idx = (unsigned int)(hw * NCLS + c);
                        u.sel.keysL[pos] = ((unsigned long long)__float_as_uint(s) << 32)
                                         | (unsigned long long)(0xFFFFFFFFu - idx);
                    }
                }
            }
        }
    } else {
        // ---- collect keys with bin >= cut (ballot-compacted, proven)
        unsigned int cutb = s_cut;
        for (unsigned int i = tid; i < S; i += 1024){
            unsigned long long k = g_key[n][i];
            float s = __uint_as_float((unsigned int)(k >> 32));
            bool pass = ((unsigned int)(int)(s * 4096.0f)) >= cutb;
            unsigned long long mb = __ballot(pass);
            unsigned int wcnt_ = (unsigned int)__popcll(mb);
            unsigned int base = 0;
            if (lane == 0 && wcnt_) base = atomicAdd(&lcnt, wcnt_);
            base = (unsigned int)__builtin_amdgcn_readfirstlane((int)base);
            if (pass){
                unsigned int p = base + (unsigned int)__popcll(mb & ((1ull << lane) - 1ull));
                if (p < CANDL) u.sel.keysL[p] = k;
            }
        }
    }
    __syncthreads();

    int C = (int)(lcnt < CANDL ? lcnt : CANDL);
    unsigned long long kk = 0ull;
    if (C <= 1024){
        // ---- hybrid bitonic Nsort=1024, 1 elem/thread (typical: Cest ~ 1000-1015)
        for (int i = C + tid; i < 1024; i += 1024) u.sel.keysL[i] = 0ull;
        __syncthreads();
        unsigned long long va = u.sel.keysL[tid];
        REGSTEP1(2,1)
        REGSTEP1(4,2)  REGSTEP1(4,1)
        REGSTEP1(8,4)  REGSTEP1(8,2)  REGSTEP1(8,1)
        REGSTEP1(16,8) REGSTEP1(16,4) REGSTEP1(16,2) REGSTEP1(16,1)
        REGSTEP1(32,16) REGSTEP1(32,8) REGSTEP1(32,4) REGSTEP1(32,2) REGSTEP1(32,1)
        REGSTEP1(64,32) REGSTEP1(64,16) REGSTEP1(64,8) REGSTEP1(64,4) REGSTEP1(64,2) REGSTEP1(64,1)
        for (int k = 128; k <= 1024; k <<= 1){
            u.sel.keysL[tid] = va;
            __syncthreads();
            for (int j = k >> 1; j >= 64; j >>= 1){
                if (tid < 512){
                    int i  = ((tid & ~(j - 1)) << 1) | (tid & (j - 1));
                    int p2 = i | j;
                    unsigned long long a = u.sel.keysL[i];
                    unsigned long long b = u.sel.keysL[p2];
                    bool up = ((i & k) == 0);
                    if (up ? (a < b) : (a > b)){ u.sel.keysL[i] = b; u.sel.keysL[p2] = a; }
                }
                __syncthreads();
            }
            va = u.sel.keysL[tid];
            REGSTEP1(k,32) REGSTEP1(k,16) REGSTEP1(k,8) REGSTEP1(k,4) REGSTEP1(k,2) REGSTEP1(k,1)
        }
        u.sel.keysL[tid] = va;
        __syncthreads();
        // verify descending over [0,1024)
        if (tid <= 1022 && u.sel.keysL[tid] < u.sel.keysL[tid + 1]) atomicOr(&s_srtbad, 1u);
        __syncthreads();
    } else if (C <= 2048){
        // ---- hybrid bitonic Nsort=2048 (R5 proven)
        for (int i = C + tid; i < 2048; i += 1024) u.sel.keysL[i] = 0ull;
        __syncthreads();
        unsigned long long va = u.sel.keysL[tid];
        unsigned long long vb = u.sel.keysL[tid + 1024];
        REGSTEP(2,1)
        REGSTEP(4,2)  REGSTEP(4,1)
        REGSTEP(8,4)  REGSTEP(8,2)  REGSTEP(8,1)
        REGSTEP(16,8) REGSTEP(16,4) REGSTEP(16,2) REGSTEP(16,1)
        REGSTEP(32,16) REGSTEP(32,8) REGSTEP(32,4) REGSTEP(32,2) REGSTEP(32,1)
        REGSTEP(64,32) REGSTEP(64,16) REGSTEP(64,8) REGSTEP(64,4) REGSTEP(64,2) REGSTEP(64,1)
        for (int k = 128; k <= 2048; k <<= 1){
            if (k == 2048){
                unsigned long long mx = va > vb ? va : vb;
                unsigned long long mn = va > vb ? vb : va;
                va = mx; vb = mn;
            }
            u.sel.keysL[tid] = va; u.sel.keysL[tid + 1024] = vb;
            __syncthreads();
            for (int j = (k == 2048) ? 512 : (k >> 1); j >= 64; j >>= 1){
                int i  = ((tid & ~(j - 1)) << 1) | (tid & (j - 1));
                int p2 = i | j;
                unsigned long long a = u.sel.keysL[i];
                unsigned long long b = u.sel.keysL[p2];
                bool up = ((i & k) == 0);
                if (up ? (a < b) : (a > b)){ u.sel.keysL[i] = b; u.sel.keysL[p2] = a; }
                __syncthreads();
            }
            va = u.sel.keysL[tid]; vb = u.sel.keysL[tid + 1024];
            REGSTEP(k,32) REGSTEP(k,16) REGSTEP(k,8) REGSTEP(k,4) REGSTEP(k,2) REGSTEP(k,1)
        }
        u.sel.keysL[tid] = va; u.sel.keysL[tid + 1024] = vb;
        __syncthreads();
        bool bad = (u.sel.keysL[tid] < u.sel.keysL[tid + 1]);
        if (tid <= 1022) bad = bad || (u.sel.keysL[tid + 1024] < u.sel.keysL[tid + 1025]);
        if (bad) atomicOr(&s_srtbad, 1u);
        __syncthreads();
    } else {
        // rare-shape fallback: O(C^2) rank (proven path)
        for (int i = tid; i < C; i += 1024){
            unsigned long long k = u.sel.keysL[i];
            int rank = 0;
            for (int j = 0; j < C; ++j) rank += (u.sel.keysL[j] > k) ? 1 : 0;
            if (rank < TOPK) stop[rank] = k;
        }
        __syncthreads();
        if (tid < TOPK) u.sel.keysL[tid] = stop[tid];   // unify read path
        __syncthreads();
    }

    if (s_srtbad){
        // ---- safety net: re-collect (mode-appropriate) + proven plain bitonic
        if (tid == 0) lcnt = 0u;
        __syncthreads();
        unsigned int cutb = s_cut;
        if (s_flag){
            const float* cls_n = cls + (size_t)n * M;
            const float* sct_n = g_sct + n * HW;
            for (int e = tid; e < M; e += 1024){
                float p = sigmoid_exact(cls_n[e]);
                if (p > PRE_T){
                    int c = e / HW; int hw = e - c * HW;
                    float s = p * sct_n[hw];
                    if ((int)(s * 4096.0f) >= (int)cutb){
                        unsigned int pos = atomicAdd(&lcnt, 1u);
                        if (pos < CANDL){
                            unsigned int idx = (unsigned int)(hw * NCLS + c);
                            u.sel.keysL[pos] = ((unsigned long long)__float_as_uint(s) << 32)
                                             | (unsigned long long)(0xFFFFFFFFu - idx);
                        }
                    }
                }
            }
        } else {
            for (unsigned int i = tid; i < S; i += 1024){
                unsigned long long k = g_key[n][i];
                float s = __uint_as_float((unsigned int)(k >> 32));
                bool pass = ((unsigned int)(int)(s * 4096.0f)) >= cutb;
                unsigned long long mb = __ballot(pass);
                unsigned int wcnt_ = (unsigned int)__popcll(mb);
                unsigned int base = 0;
                if (lane == 0 && wcnt_) base = atomicAdd(&lcnt, wcnt_);
                base = (unsigned int)__builtin_amdgcn_readfirstlane((int)base);
                if (pass){
                    unsigned int p = base + (unsigned int)__popcll(mb & ((1ull << lane) - 1ull));
                    if (p < CANDL) u.sel.keysL[p] = k;
                }
            }
        }
        __syncthreads();
        int C2 = (int)(lcnt < CANDL ? lcnt : CANDL);
        for (int i = C2 + tid; i < 2048; i += 1024) u.sel.keysL[i] = 0ull;
        __syncthreads();
        for (int k = 2; k <= 2048; k <<= 1){
            for (int j = k >> 1; j > 0; j >>= 1){
                int i  = ((tid & ~(j - 1)) << 1) | (tid & (j - 1));
                int p2 = i | j;
                unsigned long long a = u.sel.keysL[i];
                unsigned long long b = u.sel.keysL[p2];
                bool up = ((i & k) == 0);
                if (up ? (a < b) : (a > b)){ u.sel.keysL[i] = b; u.sel.keysL[p2] = a; }
                __syncthreads();
            }
        }
    }
    kk = (tid < TOPK) ? u.sel.keysL[tid] : 0ull;
    __syncthreads();   // fence all sel reads before union reuse writes

    // ---- NMS phase (u.nms aliases u.sel — all sel reads are done)
    float rx1 = 0.f, ry1 = 0.f, rx2 = -1.f, ry2 = -1.f, rar = 1.f;
    float ihh = (float)imsz[2*n + 0];
    float iww = (float)imsz[2*n + 1];

    u.nms.keepf[tid] = 0;
    { unsigned int* wz = &u.nms.Wc[0][0];
      for (int i = tid; i < 16*80; i += 1024) wz[i] = 0u; }

    if (tid < TOPK){
        unsigned int bits = (unsigned int)(kk >> 32);
        float s = __uint_as_float(bits);
        u.nms.supp[tid] = 0;
        if (s > 0.0f){
            unsigned int idx = 0xFFFFFFFFu - (unsigned int)(kk & 0xFFFFFFFFull);
            int hw = (int)(idx / NCLS);
            int c  = (int)(idx % NCLS);
            int l  = c + 1;
            float x  = loc[2*hw], y = loc[2*hw + 1];
            float r0 = reg[((size_t)n*4 + 0)*HW + hw];
            float r1 = reg[((size_t)n*4 + 1)*HW + hw];
            float r2 = reg[((size_t)n*4 + 2)*HW + hw];
            float r3 = reg[((size_t)n*4 + 3)*HW + hw];
            float x1 = fminf(fmaxf(x - r0, 0.0f), iww - 1.0f);
            float y1 = fminf(fmaxf(y - r1, 0.0f), ihh - 1.0f);
            float x2 = fminf(fmaxf(x + r2, 0.0f), iww - 1.0f);
            float y2 = fminf(fmaxf(y + r3, 0.0f), ihh - 1.0f);
            u.nms.bxs[tid][0] = x1; u.nms.bxs[tid][1] = y1;
            u.nms.bxs[tid][2] = x2; u.nms.bxs[tid][3] = y2;
            float off = (float)l * 100000.0f;   // fp32, as reference (quantizes!)
            float a1 = x1 + off, b1 = y1 + off, a2 = x2 + off, b2 = y2 + off;
            float ar = (a2 - a1 + 1.0f) * (b2 - b1 + 1.0f);
            u.nms.ox1[tid] = a1; u.nms.oy1[tid] = b1;
            u.nms.ox2[tid] = a2; u.nms.oy2[tid] = b2; u.nms.oar[tid] = ar;
            rx1 = a1; ry1 = b1; rx2 = a2; ry2 = b2; rar = ar;
            u.nms.sc[tid] = s; u.nms.lab[tid] = l; u.nms.validf[tid] = 1;
        } else {
            u.nms.validf[tid] = 0; u.nms.sc[tid] = 0.0f; u.nms.lab[tid] = 0;
            u.nms.bxs[tid][0] = u.nms.bxs[tid][1] = 0.0f;
            u.nms.bxs[tid][2] = u.nms.bxs[tid][3] = 0.0f;
            u.nms.ox1[tid] = 0.f; u.nms.oy1[tid] = 0.f;
            u.nms.ox2[tid] = -1.f; u.nms.oy2[tid] = -1.f; u.nms.oar[tid] = 1.f;
        }
    }
    __syncthreads();

    // ---- class bucketing (stable in rank): counts -> column prefix -> scatter
    int mk = -1;
    if (tid < TOPK && u.nms.validf[tid]) mk = u.nms.lab[tid] - 1;
    if (mk >= 0) atomicAdd(&u.nms.Wc[wv][mk], 1u);
    __syncthreads();
    if (tid < NCLS){
        unsigned int acc = 0;
        for (int w = 0; w < 16; ++w){
            unsigned int v = u.nms.Wc[w][tid];
            u.nms.Wc[w][tid] = acc;
            acc += v;
        }
        u.nms.ctot[tid] = acc;            // class total
        if (acc > 64) atomicOr(&s_nmsfb, 1u);
    }
    __syncthreads();
    // parallel exclusive prefix over 80 class totals (wave-0 shfl scan)
    if (wv == 0){
        unsigned int v = u.nms.ctot[lane];            // classes 0..63
        unsigned int inc = v;
        #pragma unroll
        for (int d = 1; d < 64; d <<= 1){
            unsigned int t = __shfl_up(inc, d);
            if (lane >= d) inc += t;
        }
        u.nms.coff[lane + 1] = inc;                   // coff[1..64]
        if (lane == 0) u.nms.coff[0] = 0u;
        unsigned int base = __shfl(inc, 63);
        unsigned int inc2 = (lane < 16) ? u.nms.ctot[64 + lane] : 0u;
        #pragma unroll
        for (int d = 1; d < 16; d <<= 1){
            unsigned int t = __shfl_up(inc2, d);
            if (lane >= d) inc2 += t;
        }
        if (lane < 16) u.nms.coff[65 + lane] = base + inc2;   // coff[65..80]
    }
    __syncthreads();

    if (!s_nmsfb){
        // stable within-wave same-class prefix via shfl (register-only)
        int below = 0;
        for (int l = 0; l < 64; ++l){
            int ok = __shfl(mk, l);
            below += (l < lane && ok == mk) ? 1 : 0;
        }
        if (mk >= 0){
            unsigned int pos = u.nms.coff[mk] + u.nms.Wc[wv][mk] + (unsigned int)below;
            u.nms.ord[pos] = (unsigned short)tid;
        }
        __syncthreads();

        // per-class greedy NMS, all in registers (wave w owns classes w, w+16, ...)
        for (int k = wv; k < NCLS; k += 16){
            int base = (int)u.nms.coff[k];
            int ck   = (int)u.nms.coff[k + 1] - base;
            if (ck <= 0) continue;
            int rr = (lane < ck) ? (int)u.nms.ord[base + lane] : -1;
            float bx1 = 0.f, by1 = 0.f, bx2 = -1.f, by2 = -1.f, bar = 1.f;
            if (rr >= 0){
                bx1 = u.nms.ox1[rr]; by1 = u.nms.oy1[rr];
                bx2 = u.nms.ox2[rr]; by2 = u.nms.oy2[rr]; bar = u.nms.oar[rr];
            }
            int sup = 0;
            for (int p = 0; p < ck; ++p){
                int keep_p = !__shfl(sup, p);          // wave-uniform
                if (keep_p){
                    float px1 = __shfl(bx1, p), py1 = __shfl(by1, p);
                    float px2 = __shfl(bx2, p), py2 = __shfl(by2, p);
                    float par = __shfl(bar, p);
                    if (lane > p && rr >= 0){
                        float ix1 = fmaxf(px1, bx1);
                        float iy1 = fmaxf(py1, by1);
                        float ix2 = fminf(px2, bx2);
                        float iy2 = fminf(py2, by2);
                        float iw_ = fmaxf(ix2 - ix1 + 1.0f, 0.0f);
                        float ih_ = fmaxf(iy2 - iy1 + 1.0f, 0.0f);
                        float inter = iw_ * ih_;
                        float iou = inter / (par + bar - inter);
                        if (iou > NMS_T) sup = 1;
                    }
                }
            }
            if (rr >= 0) u.nms.keepf[rr] = sup ? 0 : 1;
        }
        __syncthreads();

        // compact kept candidates in global rank order -> keeplist[0..cnt)
        int kf = (int)u.nms.keepf[tid];
        unsigned long long mb = __ballot(kf != 0);
        if (lane == 0) u.nms.wcnt[wv] = (unsigned int)__popcll(mb);
        __syncthreads();
        if (wv == 0){
            unsigned int v = (lane < 16) ? u.nms.wcnt[lane] : 0u;
            unsigned int orig = v;
            for (int d = 1; d < 16; d <<= 1){
                unsigned int t = __shfl_up(v, d);
                if (lane >= d) v += t;
            }
            if (lane < 16) u.nms.wcnt[lane] = v - orig;   // exclusive
            if (lane == 15) s_cnt = (v < OUTK ? v : OUTK);
        }
        __syncthreads();
        if (kf){
            unsigned int slot = u.nms.wcnt[wv] + (unsigned int)__popcll(mb & ((1ull << lane) - 1ull));
            if (slot < OUTK) u.nms.keeplist[slot] = tid;
        }
    } else {
        // ---- fallback: original serial NMS scan (c_k > 64; ~never on this data)
        int cnt = 0;
        for (int i = 0; i < TOPK; ++i){
            bool keep_i = u.nms.validf[i] && !u.nms.supp[i];
            if (keep_i){
                if (tid == 0) u.nms.keeplist[cnt] = i;
                if (tid < TOPK && tid != i){
                    float ix1 = fmaxf(u.nms.ox1[i], rx1);
                    float iy1 = fmaxf(u.nms.oy1[i], ry1);
                    float ix2 = fminf(u.nms.ox2[i], rx2);
                    float iy2 = fminf(u.nms.oy2[i], ry2);
                    float iw_ = fmaxf(ix2 - ix1 + 1.0f, 0.0f);
                    float ih_ = fmaxf(iy2 - iy1 + 1.0f, 0.0f);
                    float inter = iw_ * ih_;
                    float iou = inter / (u.nms.oar[i] + rar - inter);
                    if (iou > NMS_T) u.nms.supp[tid] = 1;
                }
                cnt++;
                __syncthreads();
                if (cnt == OUTK) break;
            }
        }
        if (tid == 0) s_cnt = (unsigned int)(cnt < OUTK ? cnt : OUTK);
    }
    __syncthreads();

    int cnt = (int)s_cnt;
    if (tid < OUTK){
        float r0=0.f,r1=0.f,r2=0.f,r3=0.f,r4=0.f,r5=0.f;
        if (tid < cnt){
            int i = u.nms.keeplist[tid];
            r0 = u.nms.bxs[i][0]; r1 = u.nms.bxs[i][1];
            r2 = u.nms.bxs[i][2]; r3 = u.nms.bxs[i][3];
            r4 = sqrtf(u.nms.sc[i]); r5 = (float)u.nms.lab[i];
        }
        float* o = out + ((size_t)n*OUTK + tid)*6;
        o[0]=r0; o[1]=r1; o[2]=r2; o[3]=r3; o[4]=r4; o[5]=r5;
    }
}

extern "C" void kernel_launch(void* const* d_in, const int* in_sizes, int n_in,
                              void* d_out, int out_size, void* d_ws, size_t ws_size,
                              hipStream_t stream){
    const float* loc  = (const float*)d_in[0];
    const float* cls  = (const float*)d_in[1];
    const float* reg  = (const float*)d_in[2];
    const float* cent = (const float*)d_in[3];
    const int*   imsz = (const int*)d_in[4];
    float* out = (float*)d_out;

    hipLaunchKernelGGL(k0_init,       dim3(625),                 dim3(512),  0, stream, cent);
    hipLaunchKernelGGL(k1_spill,      dim3((M+4095)/4096, NIMG), dim3(1024), 0, stream, cls);
    hipLaunchKernelGGL(k2_select_nms, dim3(NIMG),                dim3(1024), 0, stream,
                       cls, loc, reg, imsz, out);
}

// Round 7
// 240.413 us; speedup vs baseline: 1.0689x; 1.0371x over previous
//
#include <hip/hip_runtime.h>
#include <math.h>

#define NIMG 8
#define NCLS 80
#define HW 40000
#define M (NCLS*HW)          // 3,200,000 per image
#define UBINS 4096           // uniform bins over s in [0,1): bin = (int)(s*4096)
#define CANDL 4096           // collect cap (fallback path)
#define SPILL_CAP 65536
#define BCAP 1024
#define TOPK 1000
#define OUTK 100
#define PRE_T 0.05f
#define NMS_T 0.6f
#define FLOOR_BITS 0x3E800000u
#define FLOOR_SAFE 0.2494f

// device-global scratch; counters re-zeroed every call, rest guarded by counts
__device__ unsigned int       g_scnt[NIMG][32];    // padded: 128B per image
__device__ unsigned int       g_ovf[NIMG];
__device__ unsigned int       g_hist[NIMG][UBINS]; // 128 KB: built by k1 (R6)
__device__ float              g_xthr[NIMG * HW];   // 1.25 MB, L2-resident
__device__ float              g_sct[NIMG * HW];    // exact sigmoid(centerness)
__device__ unsigned long long g_key[NIMG][SPILL_CAP];

__device__ __forceinline__ float sigmoid_exact(float x){
    return 1.0f / (1.0f + expf(-x));   // bit-matches ref (absmax 0 across sessions)
}

__device__ __forceinline__ unsigned long long shfl_xor_u64(unsigned long long v, int j){
    int lo = __shfl_xor((int)(unsigned int)(v & 0xffffffffull), j);
    int hi = __shfl_xor((int)(unsigned int)(v >> 32), j);
    return ((unsigned long long)(unsigned int)hi << 32) | (unsigned long long)(unsigned int)lo;
}

// k0: zero counters + g_hist; exact sct table; xthr = logit(FLOOR_SAFE/sct).
__global__ void k0_init(const float* __restrict__ cent){
    int t = blockIdx.x * blockDim.x + threadIdx.x;
    if (t < NIMG * 32) ((unsigned int*)g_scnt)[t] = 0u;
    if (t < NIMG) g_ovf[t] = 0u;
    if (t < NIMG * UBINS) ((unsigned int*)g_hist)[t] = 0u;
    if (t < NIMG * HW){
        float pct = sigmoid_exact(cent[t]);
        g_sct[t] = pct;
        float a = FLOOR_SAFE / pct;
        float xt;
        if (a >= 1.0f) xt = 3.0e38f;
        else {
            float am = fminf(a, 0.98f);
            xt = logf(am / (1.0f - am));
        }
        g_xthr[t] = xt;
    }
}

// k1 (R7): same proven per-element logic (compare vs xthr -> rare exact-key spill
// to LDS -> block atomic -> tail writeback; g_hist atomic from R6), re-partitioned
// for ILP: 512-thread blocks, 4 sub-tiles/thread, all 8 loads issued up-front
// (4x MLP), 2x fewer barrier/atomic sequences. Key SET unchanged (every element
// examined once, same math); g_key order changes benignly (k2 totally orders).
// R6 counters motivating this: dur 71.5us, VALUBusy 14%, hbm 11% peak ->
// latency/block-overhead bound, 3.5x above the ~20us stream floor.
__global__ void __launch_bounds__(512) k1_spill(const float* __restrict__ cls){
    const int n   = blockIdx.y;
    const int tid = threadIdx.x;
    const int eb  = blockIdx.x * 8192 + tid * 4;   // sub-tile i at eb + i*2048
    __shared__ unsigned long long skey[BCAP];
    __shared__ unsigned int lcnt, lbase;
    if (tid == 0) lcnt = 0u;
    __syncthreads();

    // issue all loads up-front (static-index unroll -> registers, 8 loads in flight)
    float4 xa[4], ta[4];
    int    ca[4], ha[4];
    bool   va[4];
    #pragma unroll
    for (int i = 0; i < 4; ++i){
        int e = eb + i * 2048;
        va[i] = (e < M);
        if (va[i]){
            ca[i] = e / HW;
            ha[i] = e - ca[i] * HW;          // float4 never crosses class row (HW%4==0)
            xa[i] = *(const float4*)(cls + (size_t)n * M + e);
            ta[i] = *(const float4*)(g_xthr + n * HW + ha[i]);
        }
    }

    #define SPILL1(HWI, CI, XV, THV) \
    if (XV >= THV){ \
        float p_ = sigmoid_exact(XV); \
        if (p_ > PRE_T){ \
            float s_ = p_ * g_sct[n * HW + (HWI)]; \
            unsigned long long key_ = ((unsigned long long)__float_as_uint(s_) << 32) \
                | (unsigned long long)(0xFFFFFFFFu - (unsigned int)((HWI) * NCLS + (CI))); \
            atomicAdd(&g_hist[n][(int)(s_ * 4096.0f)], 1u); \
            unsigned int pp_ = atomicAdd(&lcnt, 1u); \
            if (pp_ < BCAP) skey[pp_] = key_; \
        } \
    }
    #pragma unroll
    for (int i = 0; i < 4; ++i){
        if (va[i]){
            SPILL1(ha[i] + 0, ca[i], xa[i].x, ta[i].x)
            SPILL1(ha[i] + 1, ca[i], xa[i].y, ta[i].y)
            SPILL1(ha[i] + 2, ca[i], xa[i].z, ta[i].z)
            SPILL1(ha[i] + 3, ca[i], xa[i].w, ta[i].w)
        }
    }
    #undef SPILL1

    __syncthreads();
    unsigned int raw = lcnt;
    unsigned int cnt = raw < BCAP ? raw : BCAP;
    if (tid == 0){
        lbase = cnt ? atomicAdd(&g_scnt[n][0], cnt) : 0u;
        if (raw > BCAP) g_ovf[n] = 1u;
    }
    __syncthreads();
    unsigned int base = lbase;
    for (unsigned int i = tid; i < cnt; i += 512){
        unsigned int pos = base + i;
        if (pos < SPILL_CAP) g_key[n][pos] = skey[i];
    }
}

struct SelPhase {
    unsigned int hist[UBINS];                 // 16 KB (loaded from g_hist, 4 iters)
    unsigned int cs[256];                     // coarse sums -> IN-PLACE suffix sums
    unsigned int wtot[4];                     // per-wave suffix totals
    unsigned long long keysL[CANDL];          // 32 KB (collect + sort buffer)
};
struct NmsPhase {
    float ox1[TOPK], oy1[TOPK], ox2[TOPK], oy2[TOPK], oar[TOPK];  // offset boxes (fp32 as ref)
    float bxs[TOPK][4];
    float sc[TOPK];
    int   lab[TOPK];
    int   keeplist[OUTK];
    unsigned int  Wc[16][80];     // per-wave per-class counts -> column-exclusive prefixes
    unsigned int  ctot[80];       // class totals (input to parallel prefix)
    unsigned int  coff[81];       // class-exclusive prefix
    unsigned int  wcnt[16];       // keep-compaction wave counts -> prefix
    unsigned short ord[1024];     // class-bucketed candidate ranks (stable in rank)
    unsigned char validf[TOPK];
    unsigned char supp[TOPK];     // used by the serial-NMS fallback only
    unsigned char keepf[1024];
};
union KU { SelPhase sel; NmsPhase nms; };     // ~55 KB (phases don't overlap)

// Register/shfl bitonic steps (region (idx & k)==0 descending; proven R5).
#define REGSTEP(K_, J_) { \
    unsigned long long pa = shfl_xor_u64(va, (J_)); \
    unsigned long long pb = shfl_xor_u64(vb, (J_)); \
    bool fa = ((tid & (J_)) == 0); \
    bool da = ((tid & (K_)) == 0); \
    bool db = (((tid + 1024) & (K_)) == 0); \
    va = (fa == da) ? (va > pa ? va : pa) : (va < pa ? va : pa); \
    vb = (fa == db) ? (vb > pb ? vb : pb) : (vb < pb ? vb : pb); \
}
#define REGSTEP1(K_, J_) { \
    unsigned long long pa = shfl_xor_u64(va, (J_)); \
    bool fa = ((tid & (J_)) == 0); \
    bool da = ((tid & (K_)) == 0); \
    va = (fa == da) ? (va > pa ? va : pa) : (va < pa ? va : pa); \
}

// k2 (R6, unchanged): g_hist load -> parallel cut-find -> collect -> hybrid
// bitonic sized to C (1024/2048) with verify + safety net -> per-class reg NMS.
__global__ void __launch_bounds__(1024) k2_select_nms(const float* __restrict__ cls,
                                                      const float* __restrict__ loc,
                                                      const float* __restrict__ reg,
                                                      const int*   __restrict__ imsz,
                                                      float* __restrict__ out){
    const int n = blockIdx.x;
    const int tid = threadIdx.x;
    const int lane = tid & 63;
    const int wv   = tid >> 6;
    __shared__ KU u;
    __shared__ unsigned long long stop[TOPK];
    __shared__ unsigned int lcnt, s_cut, s_flag, s_nmsfb, s_cnt, s_c, s_csn, s_Cest, s_srtbad;

    for (int i = tid; i < UBINS; i += 1024) u.sel.hist[i] = g_hist[n][i];
    if (tid == 0){ s_nmsfb = 0u; s_srtbad = 0u; s_c = 0xFFFFFFFFu; s_csn = 0u;
                   s_Cest = 0u; s_cut = 0u; lcnt = 0u; }
    if (tid < TOPK) stop[tid] = 0ull;
    __syncthreads();

    unsigned int scnt_raw = g_scnt[n][0];
    unsigned int ovf_f    = g_ovf[n];
    unsigned int S = scnt_raw < SPILL_CAP ? scnt_raw : SPILL_CAP;

    if (tid < 256){
        unsigned int s = 0;
        int base = tid * 16;
        #pragma unroll
        for (int i = 0; i < 16; ++i) s += u.sel.hist[base + i];
        u.sel.cs[tid] = s;
    }
    __syncthreads();
    // in-place inclusive SUFFIX scan of cs[256] (4 waves, shfl_down)
    if (tid < 256){
        unsigned int v = u.sel.cs[tid];
        #pragma unroll
        for (int d = 1; d < 64; d <<= 1){
            unsigned int t = __shfl_down(v, d);
            if (lane + d < 64) v += t;
        }
        if (lane == 0) u.sel.wtot[wv] = v;
        u.sel.cs[tid] = v;
    }
    __syncthreads();
    if (tid < 256){
        unsigned int tail = 0;
        for (int w = wv + 1; w < 4; ++w) tail += u.sel.wtot[w];
        u.sel.cs[tid] += tail;      // cs now holds global suffix sums css[t]
    }
    __syncthreads();
    // coarse crossing: c* = max{t: css[t] >= TOPK}
    if (tid < 256){
        unsigned int a = u.sel.cs[tid];
        unsigned int b = (tid == 255) ? 0u : u.sel.cs[tid + 1];
        if (a >= TOPK && b < TOPK){ s_c = (unsigned int)tid; s_csn = b; }
    }
    __syncthreads();
    // fine crossing within block c* (wave 0, 16-lane suffix scan)
    if (wv == 0 && s_c != 0xFFFFFFFFu){
        unsigned int cst = s_c;
        unsigned int h = (lane < 16) ? u.sel.hist[cst * 16 + lane] : 0u;
        #pragma unroll
        for (int d = 1; d < 16; d <<= 1){
            unsigned int t = __shfl_down(h, d);
            if (lane + d < 16) h += t;
        }
        unsigned int gs  = h + s_csn;            // global suffix at bin cst*16+lane
        unsigned int gsn = __shfl_down(gs, 1);
        if (lane == 15) gsn = s_csn;
        if (lane < 16 && gs >= TOPK && gsn < TOPK){ s_cut = cst * 16 + lane; s_Cest = gs; }
    }
    __syncthreads();
    if (tid == 0){
        unsigned int c025 = u.sel.cs[64];        // suffix at bin 1024 == count{s>=0.25}
        s_flag = (scnt_raw > SPILL_CAP) || ovf_f || (s_c == 0xFFFFFFFFu) ||
                 (c025 < TOPK) || (s_Cest > CANDL) ? 1u : 0u;
    }
    __syncthreads();

    if (s_flag){
        // ---- fallback: exact full rescan (serial cut-find kept verbatim; ~never)
        for (int i = tid; i < UBINS; i += 1024) u.sel.hist[i] = 0u;
        __syncthreads();
        const float* cls_n = cls + (size_t)n * M;
        const float* sct_n = g_sct + n * HW;
        for (int e = tid; e < M; e += 1024){
            float p = sigmoid_exact(cls_n[e]);
            if (p > PRE_T){
                int c = e / HW; int hw = e - c * HW;
                float s = p * sct_n[hw];
                atomicAdd(&u.sel.hist[(int)(s * 4096.0f)], 1u);
            }
        }
        __syncthreads();
        if (tid < 256){
            unsigned int s = 0;
            int base = tid * 16;
            #pragma unroll
            for (int i = 0; i < 16; ++i) s += u.sel.hist[base + i];
            u.sel.cs[tid] = s;
        }
        __syncthreads();
        if (tid == 0){
            unsigned int acc = 0; int cut = 0; int c = 255;
            for (; c >= 0; --c){ if (acc + u.sel.cs[c] >= TOPK) break; acc += u.sel.cs[c]; }
            if (c >= 0){
                int b = c*16 + 15;
                for (;; --b){ acc += u.sel.hist[b]; if (acc >= TOPK || b == c*16) break; }
                cut = b;
            }
            while (acc > CANDL && cut < UBINS){ acc -= u.sel.hist[cut]; cut++; }
            s_cut = (unsigned int)cut;
        }
        __syncthreads();
        unsigned int cutb = s_cut;
        for (int e = tid; e < M; e += 1024){
            float p = sigmoid_exact(cls_n[e]);
            if (p > PRE_T){
                int c = e / HW; int hw = e - c * HW;
                float s = p * sct_n[hw];
                if ((int)(s * 4096.0f) >= (int)cutb){
                    unsigned int pos = atomicAdd(&lcnt, 1u);
                    if (pos < CANDL){
                        unsigned int idx = (unsigned int)(hw * NCLS + c);
                        u.sel.keysL[pos] = ((unsigned long long)__float_as_uint(s) << 32)
                                         | (unsigned long long)(0xFFFFFFFFu - idx);
                    }
                }
            }
        }
    } else {
        // ---- collect keys with bin >= cut (ballot-compacted, proven)
        unsigned int cutb = s_cut;
        for (unsigned int i = tid; i < S; i += 1024){
            unsigned long long k = g_key[n][i];
            float s = __uint_as_float((unsigned int)(k >> 32));
            bool pass = ((unsigned int)(int)(s * 4096.0f)) >= cutb;
            unsigned long long mb = __ballot(pass);
            unsigned int wcnt_ = (unsigned int)__popcll(mb);
            unsigned int base = 0;
            if (lane == 0 && wcnt_) base = atomicAdd(&lcnt, wcnt_);
            base = (unsigned int)__builtin_amdgcn_readfirstlane((int)base);
            if (pass){
                unsigned int p = base + (unsigned int)__popcll(mb & ((1ull << lane) - 1ull));
                if (p < CANDL) u.sel.keysL[p] = k;
            }
        }
    }
    __syncthreads();

    int C = (int)(lcnt < CANDL ? lcnt : CANDL);
    unsigned long long kk = 0ull;
    if (C <= 1024){
        // ---- hybrid bitonic Nsort=1024, 1 elem/thread (typical: Cest ~ 1000-1015)
        for (int i = C + tid; i < 1024; i += 1024) u.sel.keysL[i] = 0ull;
        __syncthreads();
        unsigned long long va = u.sel.keysL[tid];
        REGSTEP1(2,1)
        REGSTEP1(4,2)  REGSTEP1(4,1)
        REGSTEP1(8,4)  REGSTEP1(8,2)  REGSTEP1(8,1)
        REGSTEP1(16,8) REGSTEP1(16,4) REGSTEP1(16,2) REGSTEP1(16,1)
        REGSTEP1(32,16) REGSTEP1(32,8) REGSTEP1(32,4) REGSTEP1(32,2) REGSTEP1(32,1)
        REGSTEP1(64,32) REGSTEP1(64,16) REGSTEP1(64,8) REGSTEP1(64,4) REGSTEP1(64,2) REGSTEP1(64,1)
        for (int k = 128; k <= 1024; k <<= 1){
            u.sel.keysL[tid] = va;
            __syncthreads();
            for (int j = k >> 1; j >= 64; j >>= 1){
                if (tid < 512){
                    int i  = ((tid & ~(j - 1)) << 1) | (tid & (j - 1));
                    int p2 = i | j;
                    unsigned long long a = u.sel.keysL[i];
                    unsigned long long b = u.sel.keysL[p2];
                    bool up = ((i & k) == 0);
                    if (up ? (a < b) : (a > b)){ u.sel.keysL[i] = b; u.sel.keysL[p2] = a; }
                }
                __syncthreads();
            }
            va = u.sel.keysL[tid];
            REGSTEP1(k,32) REGSTEP1(k,16) REGSTEP1(k,8) REGSTEP1(k,4) REGSTEP1(k,2) REGSTEP1(k,1)
        }
        u.sel.keysL[tid] = va;
        __syncthreads();
        // verify descending over [0,1024)
        if (tid <= 1022 && u.sel.keysL[tid] < u.sel.keysL[tid + 1]) atomicOr(&s_srtbad, 1u);
        __syncthreads();
    } else if (C <= 2048){
        // ---- hybrid bitonic Nsort=2048 (R5 proven)
        for (int i = C + tid; i < 2048; i += 1024) u.sel.keysL[i] = 0ull;
        __syncthreads();
        unsigned long long va = u.sel.keysL[tid];
        unsigned long long vb = u.sel.keysL[tid + 1024];
        REGSTEP(2,1)
        REGSTEP(4,2)  REGSTEP(4,1)
        REGSTEP(8,4)  REGSTEP(8,2)  REGSTEP(8,1)
        REGSTEP(16,8) REGSTEP(16,4) REGSTEP(16,2) REGSTEP(16,1)
        REGSTEP(32,16) REGSTEP(32,8) REGSTEP(32,4) REGSTEP(32,2) REGSTEP(32,1)
        REGSTEP(64,32) REGSTEP(64,16) REGSTEP(64,8) REGSTEP(64,4) REGSTEP(64,2) REGSTEP(64,1)
        for (int k = 128; k <= 2048; k <<= 1){
            if (k == 2048){
                unsigned long long mx = va > vb ? va : vb;
                unsigned long long mn = va > vb ? vb : va;
                va = mx; vb = mn;
            }
            u.sel.keysL[tid] = va; u.sel.keysL[tid + 1024] = vb;
            __syncthreads();
            for (int j = (k == 2048) ? 512 : (k >> 1); j >= 64; j >>= 1){
                int i  = ((tid & ~(j - 1)) << 1) | (tid & (j - 1));
                int p2 = i | j;
                unsigned long long a = u.sel.keysL[i];
                unsigned long long b = u.sel.keysL[p2];
                bool up = ((i & k) == 0);
                if (up ? (a < b) : (a > b)){ u.sel.keysL[i] = b; u.sel.keysL[p2] = a; }
                __syncthreads();
            }
            va = u.sel.keysL[tid]; vb = u.sel.keysL[tid + 1024];
            REGSTEP(k,32) REGSTEP(k,16) REGSTEP(k,8) REGSTEP(k,4) REGSTEP(k,2) REGSTEP(k,1)
        }
        u.sel.keysL[tid] = va; u.sel.keysL[tid + 1024] = vb;
        __syncthreads();
        bool bad = (u.sel.keysL[tid] < u.sel.keysL[tid + 1]);
        if (tid <= 1022) bad = bad || (u.sel.keysL[tid + 1024] < u.sel.keysL[tid + 1025]);
        if (bad) atomicOr(&s_srtbad, 1u);
        __syncthreads();
    } else {
        // rare-shape fallback: O(C^2) rank (proven path)
        for (int i = tid; i < C; i += 1024){
            unsigned long long k = u.sel.keysL[i];
            int rank = 0;
            for (int j = 0; j < C; ++j) rank += (u.sel.keysL[j] > k) ? 1 : 0;
            if (rank < TOPK) stop[rank] = k;
        }
        __syncthreads();
        if (tid < TOPK) u.sel.keysL[tid] = stop[tid];   // unify read path
        __syncthreads();
    }

    if (s_srtbad){
        // ---- safety net: re-collect (mode-appropriate) + proven plain bitonic
        if (tid == 0) lcnt = 0u;
        __syncthreads();
        unsigned int cutb = s_cut;
        if (s_flag){
            const float* cls_n = cls + (size_t)n * M;
            const float* sct_n = g_sct + n * HW;
            for (int e = tid; e < M; e += 1024){
                float p = sigmoid_exact(cls_n[e]);
                if (p > PRE_T){
                    int c = e / HW; int hw = e - c * HW;
                    float s = p * sct_n[hw];
                    if ((int)(s * 4096.0f) >= (int)cutb){
                        unsigned int pos = atomicAdd(&lcnt, 1u);
                        if (pos < CANDL){
                            unsigned int idx = (unsigned int)(hw * NCLS + c);
                            u.sel.keysL[pos] = ((unsigned long long)__float_as_uint(s) << 32)
                                             | (unsigned long long)(0xFFFFFFFFu - idx);
                        }
                    }
                }
            }
        } else {
            for (unsigned int i = tid; i < S; i += 1024){
                unsigned long long k = g_key[n][i];
                float s = __uint_as_float((unsigned int)(k >> 32));
                bool pass = ((unsigned int)(int)(s * 4096.0f)) >= cutb;
                unsigned long long mb = __ballot(pass);
                unsigned int wcnt_ = (unsigned int)__popcll(mb);
                unsigned int base = 0;
                if (lane == 0 && wcnt_) base = atomicAdd(&lcnt, wcnt_);
                base = (unsigned int)__builtin_amdgcn_readfirstlane((int)base);
                if (pass){
                    unsigned int p = base + (unsigned int)__popcll(mb & ((1ull << lane) - 1ull));
                    if (p < CANDL) u.sel.keysL[p] = k;
                }
            }
        }
        __syncthreads();
        int C2 = (int)(lcnt < CANDL ? lcnt : CANDL);
        for (int i = C2 + tid; i < 2048; i += 1024) u.sel.keysL[i] = 0ull;
        __syncthreads();
        for (int k = 2; k <= 2048; k <<= 1){
            for (int j = k >> 1; j > 0; j >>= 1){
                int i  = ((tid & ~(j - 1)) << 1) | (tid & (j - 1));
                int p2 = i | j;
                unsigned long long a = u.sel.keysL[i];
                unsigned long long b = u.sel.keysL[p2];
                bool up = ((i & k) == 0);
                if (up ? (a < b) : (a > b)){ u.sel.keysL[i] = b; u.sel.keysL[p2] = a; }
                __syncthreads();
            }
        }
    }
    kk = (tid < TOPK) ? u.sel.keysL[tid] : 0ull;
    __syncthreads();   // fence all sel reads before union reuse writes

    // ---- NMS phase (u.nms aliases u.sel — all sel reads are done)
    float rx1 = 0.f, ry1 = 0.f, rx2 = -1.f, ry2 = -1.f, rar = 1.f;
    float ihh = (float)imsz[2*n + 0];
    float iww = (float)imsz[2*n + 1];

    u.nms.keepf[tid] = 0;
    { unsigned int* wz = &u.nms.Wc[0][0];
      for (int i = tid; i < 16*80; i += 1024) wz[i] = 0u; }

    if (tid < TOPK){
        unsigned int bits = (unsigned int)(kk >> 32);
        float s = __uint_as_float(bits);
        u.nms.supp[tid] = 0;
        if (s > 0.0f){
            unsigned int idx = 0xFFFFFFFFu - (unsigned int)(kk & 0xFFFFFFFFull);
            int hw = (int)(idx / NCLS);
            int c  = (int)(idx % NCLS);
            int l  = c + 1;
            float x  = loc[2*hw], y = loc[2*hw + 1];
            float r0 = reg[((size_t)n*4 + 0)*HW + hw];
            float r1 = reg[((size_t)n*4 + 1)*HW + hw];
            float r2 = reg[((size_t)n*4 + 2)*HW + hw];
            float r3 = reg[((size_t)n*4 + 3)*HW + hw];
            float x1 = fminf(fmaxf(x - r0, 0.0f), iww - 1.0f);
            float y1 = fminf(fmaxf(y - r1, 0.0f), ihh - 1.0f);
            float x2 = fminf(fmaxf(x + r2, 0.0f), iww - 1.0f);
            float y2 = fminf(fmaxf(y + r3, 0.0f), ihh - 1.0f);
            u.nms.bxs[tid][0] = x1; u.nms.bxs[tid][1] = y1;
            u.nms.bxs[tid][2] = x2; u.nms.bxs[tid][3] = y2;
            float off = (float)l * 100000.0f;   // fp32, as reference (quantizes!)
            float a1 = x1 + off, b1 = y1 + off, a2 = x2 + off, b2 = y2 + off;
            float ar = (a2 - a1 + 1.0f) * (b2 - b1 + 1.0f);
            u.nms.ox1[tid] = a1; u.nms.oy1[tid] = b1;
            u.nms.ox2[tid] = a2; u.nms.oy2[tid] = b2; u.nms.oar[tid] = ar;
            rx1 = a1; ry1 = b1; rx2 = a2; ry2 = b2; rar = ar;
            u.nms.sc[tid] = s; u.nms.lab[tid] = l; u.nms.validf[tid] = 1;
        } else {
            u.nms.validf[tid] = 0; u.nms.sc[tid] = 0.0f; u.nms.lab[tid] = 0;
            u.nms.bxs[tid][0] = u.nms.bxs[tid][1] = 0.0f;
            u.nms.bxs[tid][2] = u.nms.bxs[tid][3] = 0.0f;
            u.nms.ox1[tid] = 0.f; u.nms.oy1[tid] = 0.f;
            u.nms.ox2[tid] = -1.f; u.nms.oy2[tid] = -1.f; u.nms.oar[tid] = 1.f;
        }
    }
    __syncthreads();

    // ---- class bucketing (stable in rank): counts -> column prefix -> scatter
    int mk = -1;
    if (tid < TOPK && u.nms.validf[tid]) mk = u.nms.lab[tid] - 1;
    if (mk >= 0) atomicAdd(&u.nms.Wc[wv][mk], 1u);
    __syncthreads();
    if (tid < NCLS){
        unsigned int acc = 0;
        for (int w = 0; w < 16; ++w){
            unsigned int v = u.nms.Wc[w][tid];
            u.nms.Wc[w][tid] = acc;
            acc += v;
        }
        u.nms.ctot[tid] = acc;            // class total
        if (acc > 64) atomicOr(&s_nmsfb, 1u);
    }
    __syncthreads();
    // parallel exclusive prefix over 80 class totals (wave-0 shfl scan)
    if (wv == 0){
        unsigned int v = u.nms.ctot[lane];            // classes 0..63
        unsigned int inc = v;
        #pragma unroll
        for (int d = 1; d < 64; d <<= 1){
            unsigned int t = __shfl_up(inc, d);
            if (lane >= d) inc += t;
        }
        u.nms.coff[lane + 1] = inc;                   // coff[1..64]
        if (lane == 0) u.nms.coff[0] = 0u;
        unsigned int base = __shfl(inc, 63);
        unsigned int inc2 = (lane < 16) ? u.nms.ctot[64 + lane] : 0u;
        #pragma unroll
        for (int d = 1; d < 16; d <<= 1){
            unsigned int t = __shfl_up(inc2, d);
            if (lane >= d) inc2 += t;
        }
        if (lane < 16) u.nms.coff[65 + lane] = base + inc2;   // coff[65..80]
    }
    __syncthreads();

    if (!s_nmsfb){
        // stable within-wave same-class prefix via shfl (register-only)
        int below = 0;
        for (int l = 0; l < 64; ++l){
            int ok = __shfl(mk, l);
            below += (l < lane && ok == mk) ? 1 : 0;
        }
        if (mk >= 0){
            unsigned int pos = u.nms.coff[mk] + u.nms.Wc[wv][mk] + (unsigned int)below;
            u.nms.ord[pos] = (unsigned short)tid;
        }
        __syncthreads();

        // per-class greedy NMS, all in registers (wave w owns classes w, w+16, ...)
        for (int k = wv; k < NCLS; k += 16){
            int base = (int)u.nms.coff[k];
            int ck   = (int)u.nms.coff[k + 1] - base;
            if (ck <= 0) continue;
            int rr = (lane < ck) ? (int)u.nms.ord[base + lane] : -1;
            float bx1 = 0.f, by1 = 0.f, bx2 = -1.f, by2 = -1.f, bar = 1.f;
            if (rr >= 0){
                bx1 = u.nms.ox1[rr]; by1 = u.nms.oy1[rr];
                bx2 = u.nms.ox2[rr]; by2 = u.nms.oy2[rr]; bar = u.nms.oar[rr];
            }
            int sup = 0;
            for (int p = 0; p < ck; ++p){
                int keep_p = !__shfl(sup, p);          // wave-uniform
                if (keep_p){
                    float px1 = __shfl(bx1, p), py1 = __shfl(by1, p);
                    float px2 = __shfl(bx2, p), py2 = __shfl(by2, p);
                    float par = __shfl(bar, p);
                    if (lane > p && rr >= 0){
                        float ix1 = fmaxf(px1, bx1);
                        float iy1 = fmaxf(py1, by1);
                        float ix2 = fminf(px2, bx2);
                        float iy2 = fminf(py2, by2);
                        float iw_ = fmaxf(ix2 - ix1 + 1.0f, 0.0f);
                        float ih_ = fmaxf(iy2 - iy1 + 1.0f, 0.0f);
                        float inter = iw_ * ih_;
                        float iou = inter / (par + bar - inter);
                        if (iou > NMS_T) sup = 1;
                    }
                }
            }
            if (rr >= 0) u.nms.keepf[rr] = sup ? 0 : 1;
        }
        __syncthreads();

        // compact kept candidates in global rank order -> keeplist[0..cnt)
        int kf = (int)u.nms.keepf[tid];
        unsigned long long mb = __ballot(kf != 0);
        if (lane == 0) u.nms.wcnt[wv] = (unsigned int)__popcll(mb);
        __syncthreads();
        if (wv == 0){
            unsigned int v = (lane < 16) ? u.nms.wcnt[lane] : 0u;
            unsigned int orig = v;
            for (int d = 1; d < 16; d <<= 1){
                unsigned int t = __shfl_up(v, d);
                if (lane >= d) v += t;
            }
            if (lane < 16) u.nms.wcnt[lane] = v - orig;   // exclusive
            if (lane == 15) s_cnt = (v < OUTK ? v : OUTK);
        }
        __syncthreads();
        if (kf){
            unsigned int slot = u.nms.wcnt[wv] + (unsigned int)__popcll(mb & ((1ull << lane) - 1ull));
            if (slot < OUTK) u.nms.keeplist[slot] = tid;
        }
    } else {
        // ---- fallback: original serial NMS scan (c_k > 64; ~never on this data)
        int cnt = 0;
        for (int i = 0; i < TOPK; ++i){
            bool keep_i = u.nms.validf[i] && !u.nms.supp[i];
            if (keep_i){
                if (tid == 0) u.nms.keeplist[cnt] = i;
                if (tid < TOPK && tid != i){
                    float ix1 = fmaxf(u.nms.ox1[i], rx1);
                    float iy1 = fmaxf(u.nms.oy1[i], ry1);
                    float ix2 = fminf(u.nms.ox2[i], rx2);
                    float iy2 = fminf(u.nms.oy2[i], ry2);
                    float iw_ = fmaxf(ix2 - ix1 + 1.0f, 0.0f);
                    float ih_ = fmaxf(iy2 - iy1 + 1.0f, 0.0f);
                    float inter = iw_ * ih_;
                    float iou = inter / (u.nms.oar[i] + rar - inter);
                    if (iou > NMS_T) u.nms.supp[tid] = 1;
                }
                cnt++;
                __syncthreads();
                if (cnt == OUTK) break;
            }
        }
        if (tid == 0) s_cnt = (unsigned int)(cnt < OUTK ? cnt : OUTK);
    }
    __syncthreads();

    int cnt = (int)s_cnt;
    if (tid < OUTK){
        float r0=0.f,r1=0.f,r2=0.f,r3=0.f,r4=0.f,r5=0.f;
        if (tid < cnt){
            int i = u.nms.keeplist[tid];
            r0 = u.nms.bxs[i][0]; r1 = u.nms.bxs[i][1];
            r2 = u.nms.bxs[i][2]; r3 = u.nms.bxs[i][3];
            r4 = sqrtf(u.nms.sc[i]); r5 = (float)u.nms.lab[i];
        }
        float* o = out + ((size_t)n*OUTK + tid)*6;
        o[0]=r0; o[1]=r1; o[2]=r2; o[3]=r3; o[4]=r4; o[5]=r5;
    }
}

extern "C" void kernel_launch(void* const* d_in, const int* in_sizes, int n_in,
                              void* d_out, int out_size, void* d_ws, size_t ws_size,
                              hipStream_t stream){
    const float* loc  = (const float*)d_in[0];
    const float* cls  = (const float*)d_in[1];
    const float* reg  = (const float*)d_in[2];
    const float* cent = (const float*)d_in[3];
    const int*   imsz = (const int*)d_in[4];
    float* out = (float*)d_out;

    hipLaunchKernelGGL(k0_init,       dim3(625),                 dim3(512),  0, stream, cent);
    hipLaunchKernelGGL(k1_spill,      dim3((M+8191)/8192, NIMG), dim3(512),  0, stream, cls);
    hipLaunchKernelGGL(k2_select_nms, dim3(NIMG),                dim3(1024), 0, stream,
                       cls, loc, reg, imsz, out);
}

// Round 9
// 240.128 us; speedup vs baseline: 1.0702x; 1.0012x over previous
//
#include <hip/hip_runtime.h>
#include <math.h>

#define NIMG 8
#define NCLS 80
#define HW 40000
#define M (NCLS*HW)          // 3,200,000 per image
#define UBINS 4096           // uniform bins over s in [0,1): bin = (int)(s*4096)
#define CANDL 4096           // collect cap (fallback path)
#define SPILL_CAP 65536
#define BCAP 1024
#define TOPK 1000
#define OUTK 100
#define PRE_T 0.05f
#define NMS_T 0.6f
#define FLOOR_BITS 0x3E800000u
#define FLOOR_SAFE 0.2494f

// device-global scratch; counters re-zeroed every call, rest guarded by counts
__device__ unsigned int       g_scnt[NIMG][32];    // padded: 128B per image
__device__ unsigned int       g_ovf[NIMG];
__device__ unsigned int       g_hist[NIMG][UBINS]; // 128 KB: built by k1 (R6)
__device__ float              g_xthr[NIMG * HW];   // 1.25 MB, L2-resident
__device__ float              g_sct[NIMG * HW];    // exact sigmoid(centerness)
__device__ unsigned long long g_key[NIMG][SPILL_CAP];

__device__ __forceinline__ float sigmoid_exact(float x){
    return 1.0f / (1.0f + expf(-x));   // bit-matches ref (absmax 0 across sessions)
}

__device__ __forceinline__ unsigned long long shfl_xor_u64(unsigned long long v, int j){
    int lo = __shfl_xor((int)(unsigned int)(v & 0xffffffffull), j);
    int hi = __shfl_xor((int)(unsigned int)(v >> 32), j);
    return ((unsigned long long)(unsigned int)hi << 32) | (unsigned long long)(unsigned int)lo;
}

// k0: zero counters + g_hist; exact sct table; xthr = logit(FLOOR_SAFE/sct).
__global__ void k0_init(const float* __restrict__ cent){
    int t = blockIdx.x * blockDim.x + threadIdx.x;
    if (t < NIMG * 32) ((unsigned int*)g_scnt)[t] = 0u;
    if (t < NIMG) g_ovf[t] = 0u;
    if (t < NIMG * UBINS) ((unsigned int*)g_hist)[t] = 0u;
    if (t < NIMG * HW){
        float pct = sigmoid_exact(cent[t]);
        g_sct[t] = pct;
        float a = FLOOR_SAFE / pct;
        float xt;
        if (a >= 1.0f) xt = 3.0e38f;
        else {
            float am = fminf(a, 0.98f);
            xt = logf(am / (1.0f - am));
        }
        g_xthr[t] = xt;
    }
}

// k1 (R8): R7's logic with REAL MLP this time. R7 postmortem: VGPR_Count=24
// proved the compiler serialized the 8 loads (needs 32 VGPRs of data alone).
// Changes: (a) 16 CONTIGUOUS elems/thread (64B spans; 16|HW so one class row
// -> 1 divide/thread, was 4; thread's loads hit 1-2 cache lines, was 4 lines
// 8KB apart); (b) __launch_bounds__(512,8): VGPR budget 64 holds all 8 float4s
// in flight. Spill predicate/key math/staging byte-identical; set unchanged.
__global__ void __launch_bounds__(512, 8) k1_spill(const float* __restrict__ cls){
    const int n   = blockIdx.y;
    const int tid = threadIdx.x;
    const int e16 = blockIdx.x * 8192 + tid * 16;  // 16 contiguous elems/thread
    __shared__ unsigned long long skey[BCAP];
    __shared__ unsigned int lcnt, lbase;
    if (tid == 0) lcnt = 0u;
    __syncthreads();

    if (e16 < M){                      // 16|M and e16 16-aligned -> full run valid
        const int c   = e16 / HW;      // 16|HW -> whole run in one class row
        const int hw0 = e16 - c * HW;
        const float* pc = cls + (size_t)n * M + e16;
        const float* pt = g_xthr + n * HW + hw0;
        float4 xa[4], ta[4];
        #pragma unroll
        for (int i = 0; i < 4; ++i){   // 8 loads issued before any consumer
            xa[i] = *(const float4*)(pc + i * 4);
            ta[i] = *(const float4*)(pt + i * 4);
        }
        #define SPILL1(HWI, XV, THV) \
        if (XV >= THV){ \
            float p_ = sigmoid_exact(XV); \
            if (p_ > PRE_T){ \
                float s_ = p_ * g_sct[n * HW + (HWI)]; \
                unsigned long long key_ = ((unsigned long long)__float_as_uint(s_) << 32) \
                    | (unsigned long long)(0xFFFFFFFFu - (unsigned int)((HWI) * NCLS + c)); \
                atomicAdd(&g_hist[n][(int)(s_ * 4096.0f)], 1u); \
                unsigned int pp_ = atomicAdd(&lcnt, 1u); \
                if (pp_ < BCAP) skey[pp_] = key_; \
            } \
        }
        #pragma unroll
        for (int i = 0; i < 4; ++i){
            SPILL1(hw0 + i*4 + 0, xa[i].x, ta[i].x)
            SPILL1(hw0 + i*4 + 1, xa[i].y, ta[i].y)
            SPILL1(hw0 + i*4 + 2, xa[i].z, ta[i].z)
            SPILL1(hw0 + i*4 + 3, xa[i].w, ta[i].w)
        }
        #undef SPILL1
    }

    __syncthreads();
    unsigned int raw = lcnt;
    unsigned int cnt = raw < BCAP ? raw : BCAP;
    if (tid == 0){
        lbase = cnt ? atomicAdd(&g_scnt[n][0], cnt) : 0u;
        if (raw > BCAP) g_ovf[n] = 1u;
    }
    __syncthreads();
    unsigned int base = lbase;
    for (unsigned int i = tid; i < cnt; i += 512){
        unsigned int pos = base + i;
        if (pos < SPILL_CAP) g_key[n][pos] = skey[i];
    }
}

struct SelPhase {
    unsigned int hist[UBINS];                 // 16 KB (loaded from g_hist, 4 iters)
    unsigned int cs[256];                     // coarse sums -> IN-PLACE suffix sums
    unsigned int wtot[4];                     // per-wave suffix totals
    unsigned long long keysL[CANDL];          // 32 KB (collect + sort buffer)
};
struct NmsPhase {
    float ox1[TOPK], oy1[TOPK], ox2[TOPK], oy2[TOPK], oar[TOPK];  // offset boxes (fp32 as ref)
    float bxs[TOPK][4];
    float sc[TOPK];
    int   lab[TOPK];
    int   keeplist[OUTK];
    unsigned int  Wc[16][80];     // per-wave per-class counts -> column-exclusive prefixes
    unsigned int  ctot[80];       // class totals (input to parallel prefix)
    unsigned int  coff[81];       // class-exclusive prefix
    unsigned int  wcnt[16];       // keep-compaction wave counts -> prefix
    unsigned short ord[1024];     // class-bucketed candidate ranks (stable in rank)
    unsigned char validf[TOPK];
    unsigned char supp[TOPK];     // used by the serial-NMS fallback only
    unsigned char keepf[1024];
};
union KU { SelPhase sel; NmsPhase nms; };     // ~55 KB (phases don't overlap)

// Register/shfl bitonic steps (region (idx & k)==0 descending; proven R5).
#define REGSTEP(K_, J_) { \
    unsigned long long pa = shfl_xor_u64(va, (J_)); \
    unsigned long long pb = shfl_xor_u64(vb, (J_)); \
    bool fa = ((tid & (J_)) == 0); \
    bool da = ((tid & (K_)) == 0); \
    bool db = (((tid + 1024) & (K_)) == 0); \
    va = (fa == da) ? (va > pa ? va : pa) : (va < pa ? va : pa); \
    vb = (fa == db) ? (vb > pb ? vb : pb) : (vb < pb ? vb : pb); \
}
#define REGSTEP1(K_, J_) { \
    unsigned long long pa = shfl_xor_u64(va, (J_)); \
    bool fa = ((tid & (J_)) == 0); \
    bool da = ((tid & (K_)) == 0); \
    va = (fa == da) ? (va > pa ? va : pa) : (va < pa ? va : pa); \
}

// k2 (R6, unchanged): g_hist load -> parallel cut-find -> collect -> hybrid
// bitonic sized to C (1024/2048) with verify + safety net -> per-class reg NMS.
__global__ void __launch_bounds__(1024) k2_select_nms(const float* __restrict__ cls,
                                                      const float* __restrict__ loc,
                                                      const float* __restrict__ reg,
                                                      const int*   __restrict__ imsz,
                                                      float* __restrict__ out){
    const int n = blockIdx.x;
    const int tid = threadIdx.x;
    const int lane = tid & 63;
    const int wv   = tid >> 6;
    __shared__ KU u;
    __shared__ unsigned long long stop[TOPK];
    __shared__ unsigned int lcnt, s_cut, s_flag, s_nmsfb, s_cnt, s_c, s_csn, s_Cest, s_srtbad;

    for (int i = tid; i < UBINS; i += 1024) u.sel.hist[i] = g_hist[n][i];
    if (tid == 0){ s_nmsfb = 0u; s_srtbad = 0u; s_c = 0xFFFFFFFFu; s_csn = 0u;
                   s_Cest = 0u; s_cut = 0u; lcnt = 0u; }
    if (tid < TOPK) stop[tid] = 0ull;
    __syncthreads();

    unsigned int scnt_raw = g_scnt[n][0];
    unsigned int ovf_f    = g_ovf[n];
    unsigned int S = scnt_raw < SPILL_CAP ? scnt_raw : SPILL_CAP;

    if (tid < 256){
        unsigned int s = 0;
        int base = tid * 16;
        #pragma unroll
        for (int i = 0; i < 16; ++i) s += u.sel.hist[base + i];
        u.sel.cs[tid] = s;
    }
    __syncthreads();
    // in-place inclusive SUFFIX scan of cs[256] (4 waves, shfl_down)
    if (tid < 256){
        unsigned int v = u.sel.cs[tid];
        #pragma unroll
        for (int d = 1; d < 64; d <<= 1){
            unsigned int t = __shfl_down(v, d);
            if (lane + d < 64) v += t;
        }
        if (lane == 0) u.sel.wtot[wv] = v;
        u.sel.cs[tid] = v;
    }
    __syncthreads();
    if (tid < 256){
        unsigned int tail = 0;
        for (int w = wv + 1; w < 4; ++w) tail += u.sel.wtot[w];
        u.sel.cs[tid] += tail;      // cs now holds global suffix sums css[t]
    }
    __syncthreads();
    // coarse crossing: c* = max{t: css[t] >= TOPK}
    if (tid < 256){
        unsigned int a = u.sel.cs[tid];
        unsigned int b = (tid == 255) ? 0u : u.sel.cs[tid + 1];
        if (a >= TOPK && b < TOPK){ s_c = (unsigned int)tid; s_csn = b; }
    }
    __syncthreads();
    // fine crossing within block c* (wave 0, 16-lane suffix scan)
    if (wv == 0 && s_c != 0xFFFFFFFFu){
        unsigned int cst = s_c;
        unsigned int h = (lane < 16) ? u.sel.hist[cst * 16 + lane] : 0u;
        #pragma unroll
        for (int d = 1; d < 16; d <<= 1){
            unsigned int t = __shfl_down(h, d);
            if (lane + d < 16) h += t;
        }
        unsigned int gs  = h + s_csn;            // global suffix at bin cst*16+lane
        unsigned int gsn = __shfl_down(gs, 1);
        if (lane == 15) gsn = s_csn;
        if (lane < 16 && gs >= TOPK && gsn < TOPK){ s_cut = cst * 16 + lane; s_Cest = gs; }
    }
    __syncthreads();
    if (tid == 0){
        unsigned int c025 = u.sel.cs[64];        // suffix at bin 1024 == count{s>=0.25}
        s_flag = (scnt_raw > SPILL_CAP) || ovf_f || (s_c == 0xFFFFFFFFu) ||
                 (c025 < TOPK) || (s_Cest > CANDL) ? 1u : 0u;
    }
    __syncthreads();

    if (s_flag){
        // ---- fallback: exact full rescan (serial cut-find kept verbatim; ~never)
        for (int i = tid; i < UBINS; i += 1024) u.sel.hist[i] = 0u;
        __syncthreads();
        const float* cls_n = cls + (size_t)n * M;
        const float* sct_n = g_sct + n * HW;
        for (int e = tid; e < M; e += 1024){
            float p = sigmoid_exact(cls_n[e]);
            if (p > PRE_T){
                int c = e / HW; int hw = e - c * HW;
                float s = p * sct_n[hw];
                atomicAdd(&u.sel.hist[(int)(s * 4096.0f)], 1u);
            }
        }
        __syncthreads();
        if (tid < 256){
            unsigned int s = 0;
            int base = tid * 16;
            #pragma unroll
            for (int i = 0; i < 16; ++i) s += u.sel.hist[base + i];
            u.sel.cs[tid] = s;
        }
        __syncthreads();
        if (tid == 0){
            unsigned int acc = 0; int cut = 0; int c = 255;
            for (; c >= 0; --c){ if (acc + u.sel.cs[c] >= TOPK) break; acc += u.sel.cs[c]; }
            if (c >= 0){
                int b = c*16 + 15;
                for (;; --b){ acc += u.sel.hist[b]; if (acc >= TOPK || b == c*16) break; }
                cut = b;
            }
            while (acc > CANDL && cut < UBINS){ acc -= u.sel.hist[cut]; cut++; }
            s_cut = (unsigned int)cut;
        }
        __syncthreads();
        unsigned int cutb = s_cut;
        for (int e = tid; e < M; e += 1024){
            float p = sigmoid_exact(cls_n[e]);
            if (p > PRE_T){
                int c = e / HW; int hw = e - c * HW;
                float s = p * sct_n[hw];
                if ((int)(s * 4096.0f) >= (int)cutb){
                    unsigned int pos = atomicAdd(&lcnt, 1u);
                    if (pos < CANDL){
                        unsigned int idx = (unsigned int)(hw * NCLS + c);
                        u.sel.keysL[pos] = ((unsigned long long)__float_as_uint(s) << 32)
                                         | (unsigned long long)(0xFFFFFFFFu - idx);
                    }
                }
            }
        }
    } else {
        // ---- collect keys with bin >= cut (ballot-compacted, proven)
        unsigned int cutb = s_cut;
        for (unsigned int i = tid; i < S; i += 1024){
            unsigned long long k = g_key[n][i];
            float s = __uint_as_float((unsigned int)(k >> 32));
            bool pass = ((unsigned int)(int)(s * 4096.0f)) >= cutb;
            unsigned long long mb = __ballot(pass);
            unsigned int wcnt_ = (unsigned int)__popcll(mb);
            unsigned int base = 0;
            if (lane == 0 && wcnt_) base = atomicAdd(&lcnt, wcnt_);
            base = (unsigned int)__builtin_amdgcn_readfirstlane((int)base);
            if (pass){
                unsigned int p = base + (unsigned int)__popcll(mb & ((1ull << lane) - 1ull));
                if (p < CANDL) u.sel.keysL[p] = k;
            }
        }
    }
    __syncthreads();

    int C = (int)(lcnt < CANDL ? lcnt : CANDL);
    unsigned long long kk = 0ull;
    if (C <= 1024){
        // ---- hybrid bitonic Nsort=1024, 1 elem/thread (typical: Cest ~ 1000-1015)
        for (int i = C + tid; i < 1024; i += 1024) u.sel.keysL[i] = 0ull;
        __syncthreads();
        unsigned long long va = u.sel.keysL[tid];
        REGSTEP1(2,1)
        REGSTEP1(4,2)  REGSTEP1(4,1)
        REGSTEP1(8,4)  REGSTEP1(8,2)  REGSTEP1(8,1)
        REGSTEP1(16,8) REGSTEP1(16,4) REGSTEP1(16,2) REGSTEP1(16,1)
        REGSTEP1(32,16) REGSTEP1(32,8) REGSTEP1(32,4) REGSTEP1(32,2) REGSTEP1(32,1)
        REGSTEP1(64,32) REGSTEP1(64,16) REGSTEP1(64,8) REGSTEP1(64,4) REGSTEP1(64,2) REGSTEP1(64,1)
        for (int k = 128; k <= 1024; k <<= 1){
            u.sel.keysL[tid] = va;
            __syncthreads();
            for (int j = k >> 1; j >= 64; j >>= 1){
                if (tid < 512){
                    int i  = ((tid & ~(j - 1)) << 1) | (tid & (j - 1));
                    int p2 = i | j;
                    unsigned long long a = u.sel.keysL[i];
                    unsigned long long b = u.sel.keysL[p2];
                    bool up = ((i & k) == 0);
                    if (up ? (a < b) : (a > b)){ u.sel.keysL[i] = b; u.sel.keysL[p2] = a; }
                }
                __syncthreads();
            }
            va = u.sel.keysL[tid];
            REGSTEP1(k,32) REGSTEP1(k,16) REGSTEP1(k,8) REGSTEP1(k,4) REGSTEP1(k,2) REGSTEP1(k,1)
        }
        u.sel.keysL[tid] = va;
        __syncthreads();
        // verify descending over [0,1024)
        if (tid <= 1022 && u.sel.keysL[tid] < u.sel.keysL[tid + 1]) atomicOr(&s_srtbad, 1u);
        __syncthreads();
    } else if (C <= 2048){
        // ---- hybrid bitonic Nsort=2048 (R5 proven)
        for (int i = C + tid; i < 2048; i += 1024) u.sel.keysL[i] = 0ull;
        __syncthreads();
        unsigned long long va = u.sel.keysL[tid];
        unsigned long long vb = u.sel.keysL[tid + 1024];
        REGSTEP(2,1)
        REGSTEP(4,2)  REGSTEP(4,1)
        REGSTEP(8,4)  REGSTEP(8,2)  REGSTEP(8,1)
        REGSTEP(16,8) REGSTEP(16,4) REGSTEP(16,2) REGSTEP(16,1)
        REGSTEP(32,16) REGSTEP(32,8) REGSTEP(32,4) REGSTEP(32,2) REGSTEP(32,1)
        REGSTEP(64,32) REGSTEP(64,16) REGSTEP(64,8) REGSTEP(64,4) REGSTEP(64,2) REGSTEP(64,1)
        for (int k = 128; k <= 2048; k <<= 1){
            if (k == 2048){
                unsigned long long mx = va > vb ? va : vb;
                unsigned long long mn = va > vb ? vb : va;
                va = mx; vb = mn;
            }
            u.sel.keysL[tid] = va; u.sel.keysL[tid + 1024] = vb;
            __syncthreads();
            for (int j = (k == 2048) ? 512 : (k >> 1); j >= 64; j >>= 1){
                int i  = ((tid & ~(j - 1)) << 1) | (tid & (j - 1));
                int p2 = i | j;
                unsigned long long a = u.sel.keysL[i];
                unsigned long long b = u.sel.keysL[p2];
                bool up = ((i & k) == 0);
                if (up ? (a < b) : (a > b)){ u.sel.keysL[i] = b; u.sel.keysL[p2] = a; }
                __syncthreads();
            }
            va = u.sel.keysL[tid]; vb = u.sel.keysL[tid + 1024];
            REGSTEP(k,32) REGSTEP(k,16) REGSTEP(k,8) REGSTEP(k,4) REGSTEP(k,2) REGSTEP(k,1)
        }
        u.sel.keysL[tid] = va; u.sel.keysL[tid + 1024] = vb;
        __syncthreads();
        bool bad = (u.sel.keysL[tid] < u.sel.keysL[tid + 1]);
        if (tid <= 1022) bad = bad || (u.sel.keysL[tid + 1024] < u.sel.keysL[tid + 1025]);
        if (bad) atomicOr(&s_srtbad, 1u);
        __syncthreads();
    } else {
        // rare-shape fallback: O(C^2) rank (proven path)
        for (int i = tid; i < C; i += 1024){
            unsigned long long k = u.sel.keysL[i];
            int rank = 0;
            for (int j = 0; j < C; ++j) rank += (u.sel.keysL[j] > k) ? 1 : 0;
            if (rank < TOPK) stop[rank] = k;
        }
        __syncthreads();
        if (tid < TOPK) u.sel.keysL[tid] = stop[tid];   // unify read path
        __syncthreads();
    }

    if (s_srtbad){
        // ---- safety net: re-collect (mode-appropriate) + proven plain bitonic
        if (tid == 0) lcnt = 0u;
        __syncthreads();
        unsigned int cutb = s_cut;
        if (s_flag){
            const float* cls_n = cls + (size_t)n * M;
            const float* sct_n = g_sct + n * HW;
            for (int e = tid; e < M; e += 1024){
                float p = sigmoid_exact(cls_n[e]);
                if (p > PRE_T){
                    int c = e / HW; int hw = e - c * HW;
                    float s = p * sct_n[hw];
                    if ((int)(s * 4096.0f) >= (int)cutb){
                        unsigned int pos = atomicAdd(&lcnt, 1u);
                        if (pos < CANDL){
                            unsigned int idx = (unsigned int)(hw * NCLS + c);
                            u.sel.keysL[pos] = ((unsigned long long)__float_as_uint(s) << 32)
                                             | (unsigned long long)(0xFFFFFFFFu - idx);
                        }
                    }
                }
            }
        } else {
            for (unsigned int i = tid; i < S; i += 1024){
                unsigned long long k = g_key[n][i];
                float s = __uint_as_float((unsigned int)(k >> 32));
                bool pass = ((unsigned int)(int)(s * 4096.0f)) >= cutb;
                unsigned long long mb = __ballot(pass);
                unsigned int wcnt_ = (unsigned int)__popcll(mb);
                unsigned int base = 0;
                if (lane == 0 && wcnt_) base = atomicAdd(&lcnt, wcnt_);
                base = (unsigned int)__builtin_amdgcn_readfirstlane((int)base);
                if (pass){
                    unsigned int p = base + (unsigned int)__popcll(mb & ((1ull << lane) - 1ull));
                    if (p < CANDL) u.sel.keysL[p] = k;
                }
            }
        }
        __syncthreads();
        int C2 = (int)(lcnt < CANDL ? lcnt : CANDL);
        for (int i = C2 + tid; i < 2048; i += 1024) u.sel.keysL[i] = 0ull;
        __syncthreads();
        for (int k = 2; k <= 2048; k <<= 1){
            for (int j = k >> 1; j > 0; j >>= 1){
                int i  = ((tid & ~(j - 1)) << 1) | (tid & (j - 1));
                int p2 = i | j;
                unsigned long long a = u.sel.keysL[i];
                unsigned long long b = u.sel.keysL[p2];
                bool up = ((i & k) == 0);
                if (up ? (a < b) : (a > b)){ u.sel.keysL[i] = b; u.sel.keysL[p2] = a; }
                __syncthreads();
            }
        }
    }
    kk = (tid < TOPK) ? u.sel.keysL[tid] : 0ull;
    __syncthreads();   // fence all sel reads before union reuse writes

    // ---- NMS phase (u.nms aliases u.sel — all sel reads are done)
    float rx1 = 0.f, ry1 = 0.f, rx2 = -1.f, ry2 = -1.f, rar = 1.f;
    float ihh = (float)imsz[2*n + 0];
    float iww = (float)imsz[2*n + 1];

    u.nms.keepf[tid] = 0;
    { unsigned int* wz = &u.nms.Wc[0][0];
      for (int i = tid; i < 16*80; i += 1024) wz[i] = 0u; }

    if (tid < TOPK){
        unsigned int bits = (unsigned int)(kk >> 32);
        float s = __uint_as_float(bits);
        u.nms.supp[tid] = 0;
        if (s > 0.0f){
            unsigned int idx = 0xFFFFFFFFu - (unsigned int)(kk & 0xFFFFFFFFull);
            int hw = (int)(idx / NCLS);
            int c  = (int)(idx % NCLS);
            int l  = c + 1;
            float x  = loc[2*hw], y = loc[2*hw + 1];
            float r0 = reg[((size_t)n*4 + 0)*HW + hw];
            float r1 = reg[((size_t)n*4 + 1)*HW + hw];
            float r2 = reg[((size_t)n*4 + 2)*HW + hw];
            float r3 = reg[((size_t)n*4 + 3)*HW + hw];
            float x1 = fminf(fmaxf(x - r0, 0.0f), iww - 1.0f);
            float y1 = fminf(fmaxf(y - r1, 0.0f), ihh - 1.0f);
            float x2 = fminf(fmaxf(x + r2, 0.0f), iww - 1.0f);
            float y2 = fminf(fmaxf(y + r3, 0.0f), ihh - 1.0f);
            u.nms.bxs[tid][0] = x1; u.nms.bxs[tid][1] = y1;
            u.nms.bxs[tid][2] = x2; u.nms.bxs[tid][3] = y2;
            float off = (float)l * 100000.0f;   // fp32, as reference (quantizes!)
            float a1 = x1 + off, b1 = y1 + off, a2 = x2 + off, b2 = y2 + off;
            float ar = (a2 - a1 + 1.0f) * (b2 - b1 + 1.0f);
            u.nms.ox1[tid] = a1; u.nms.oy1[tid] = b1;
            u.nms.ox2[tid] = a2; u.nms.oy2[tid] = b2; u.nms.oar[tid] = ar;
            rx1 = a1; ry1 = b1; rx2 = a2; ry2 = b2; rar = ar;
            u.nms.sc[tid] = s; u.nms.lab[tid] = l; u.nms.validf[tid] = 1;
        } else {
            u.nms.validf[tid] = 0; u.nms.sc[tid] = 0.0f; u.nms.lab[tid] = 0;
            u.nms.bxs[tid][0] = u.nms.bxs[tid][1] = 0.0f;
            u.nms.bxs[tid][2] = u.nms.bxs[tid][3] = 0.0f;
            u.nms.ox1[tid] = 0.f; u.nms.oy1[tid] = 0.f;
            u.nms.ox2[tid] = -1.f; u.nms.oy2[tid] = -1.f; u.nms.oar[tid] = 1.f;
        }
    }
    __syncthreads();

    // ---- class bucketing (stable in rank): counts -> column prefix -> scatter
    int mk = -1;
    if (tid < TOPK && u.nms.validf[tid]) mk = u.nms.lab[tid] - 1;
    if (mk >= 0) atomicAdd(&u.nms.Wc[wv][mk], 1u);
    __syncthreads();
    if (tid < NCLS){
        unsigned int acc = 0;
        for (int w = 0; w < 16; ++w){
            unsigned int v = u.nms.Wc[w][tid];
            u.nms.Wc[w][tid] = acc;
            acc += v;
        }
        u.nms.ctot[tid] = acc;            // class total
        if (acc > 64) atomicOr(&s_nmsfb, 1u);
    }
    __syncthreads();
    // parallel exclusive prefix over 80 class totals (wave-0 shfl scan)
    if (wv == 0){
        unsigned int v = u.nms.ctot[lane];            // classes 0..63
        unsigned int inc = v;
        #pragma unroll
        for (int d = 1; d < 64; d <<= 1){
            unsigned int t = __shfl_up(inc, d);
            if (lane >= d) inc += t;
        }
        u.nms.coff[lane + 1] = inc;                   // coff[1..64]
        if (lane == 0) u.nms.coff[0] = 0u;
        unsigned int base = __shfl(inc, 63);
        unsigned int inc2 = (lane < 16) ? u.nms.ctot[64 + lane] : 0u;
        #pragma unroll
        for (int d = 1; d < 16; d <<= 1){
            unsigned int t = __shfl_up(inc2, d);
            if (lane >= d) inc2 += t;
        }
        if (lane < 16) u.nms.coff[65 + lane] = base + inc2;   // coff[65..80]
    }
    __syncthreads();

    if (!s_nmsfb){
        // stable within-wave same-class prefix via shfl (register-only)
        int below = 0;
        for (int l = 0; l < 64; ++l){
            int ok = __shfl(mk, l);
            below += (l < lane && ok == mk) ? 1 : 0;
        }
        if (mk >= 0){
            unsigned int pos = u.nms.coff[mk] + u.nms.Wc[wv][mk] + (unsigned int)below;
            u.nms.ord[pos] = (unsigned short)tid;
        }
        __syncthreads();

        // per-class greedy NMS, all in registers (wave w owns classes w, w+16, ...)
        for (int k = wv; k < NCLS; k += 16){
            int base = (int)u.nms.coff[k];
            int ck   = (int)u.nms.coff[k + 1] - base;
            if (ck <= 0) continue;
            int rr = (lane < ck) ? (int)u.nms.ord[base + lane] : -1;
            float bx1 = 0.f, by1 = 0.f, bx2 = -1.f, by2 = -1.f, bar = 1.f;
            if (rr >= 0){
                bx1 = u.nms.ox1[rr]; by1 = u.nms.oy1[rr];
                bx2 = u.nms.ox2[rr]; by2 = u.nms.oy2[rr]; bar = u.nms.oar[rr];
            }
            int sup = 0;
            for (int p = 0; p < ck; ++p){
                int keep_p = !__shfl(sup, p);          // wave-uniform
                if (keep_p){
                    float px1 = __shfl(bx1, p), py1 = __shfl(by1, p);
                    float px2 = __shfl(bx2, p), py2 = __shfl(by2, p);
                    float par = __shfl(bar, p);
                    if (lane > p && rr >= 0){
                        float ix1 = fmaxf(px1, bx1);
                        float iy1 = fmaxf(py1, by1);
                        float ix2 = fminf(px2, bx2);
                        float iy2 = fminf(py2, by2);
                        float iw_ = fmaxf(ix2 - ix1 + 1.0f, 0.0f);
                        float ih_ = fmaxf(iy2 - iy1 + 1.0f, 0.0f);
                        float inter = iw_ * ih_;
                        float iou = inter / (par + bar - inter);
                        if (iou > NMS_T) sup = 1;
                    }
                }
            }
            if (rr >= 0) u.nms.keepf[rr] = sup ? 0 : 1;
        }
        __syncthreads();

        // compact kept candidates in global rank order -> keeplist[0..cnt)
        int kf = (int)u.nms.keepf[tid];
        unsigned long long mb = __ballot(kf != 0);
        if (lane == 0) u.nms.wcnt[wv] = (unsigned int)__popcll(mb);
        __syncthreads();
        if (wv == 0){
            unsigned int v = (lane < 16) ? u.nms.wcnt[lane] : 0u;
            unsigned int orig = v;
            for (int d = 1; d < 16; d <<= 1){
                unsigned int t = __shfl_up(v, d);
                if (lane >= d) v += t;
            }
            if (lane < 16) u.nms.wcnt[lane] = v - orig;   // exclusive
            if (lane == 15) s_cnt = (v < OUTK ? v : OUTK);
        }
        __syncthreads();
        if (kf){
            unsigned int slot = u.nms.wcnt[wv] + (unsigned int)__popcll(mb & ((1ull << lane) - 1ull));
            if (slot < OUTK) u.nms.keeplist[slot] = tid;
        }
    } else {
        // ---- fallback: original serial NMS scan (c_k > 64; ~never on this data)
        int cnt = 0;
        for (int i = 0; i < TOPK; ++i){
            bool keep_i = u.nms.validf[i] && !u.nms.supp[i];
            if (keep_i){
                if (tid == 0) u.nms.keeplist[cnt] = i;
                if (tid < TOPK && tid != i){
                    float ix1 = fmaxf(u.nms.ox1[i], rx1);
                    float iy1 = fmaxf(u.nms.oy1[i], ry1);
                    float ix2 = fminf(u.nms.ox2[i], rx2);
                    float iy2 = fminf(u.nms.oy2[i], ry2);
                    float iw_ = fmaxf(ix2 - ix1 + 1.0f, 0.0f);
                    float ih_ = fmaxf(iy2 - iy1 + 1.0f, 0.0f);
                    float inter = iw_ * ih_;
                    float iou = inter / (u.nms.oar[i] + rar - inter);
                    if (iou > NMS_T) u.nms.supp[tid] = 1;
                }
                cnt++;
                __syncthreads();
                if (cnt == OUTK) break;
            }
        }
        if (tid == 0) s_cnt = (unsigned int)(cnt < OUTK ? cnt : OUTK);
    }
    __syncthreads();

    int cnt = (int)s_cnt;
    if (tid < OUTK){
        float r0=0.f,r1=0.f,r2=0.f,r3=0.f,r4=0.f,r5=0.f;
        if (tid < cnt){
            int i = u.nms.keeplist[tid];
            r0 = u.nms.bxs[i][0]; r1 = u.nms.bxs[i][1];
            r2 = u.nms.bxs[i][2]; r3 = u.nms.bxs[i][3];
            r4 = sqrtf(u.nms.sc[i]); r5 = (float)u.nms.lab[i];
        }
        float* o = out + ((size_t)n*OUTK + tid)*6;
        o[0]=r0; o[1]=r1; o[2]=r2; o[3]=r3; o[4]=r4; o[5]=r5;
    }
}

extern "C" void kernel_launch(void* const* d_in, const int* in_sizes, int n_in,
                              void* d_out, int out_size, void* d_ws, size_t ws_size,
                              hipStream_t stream){
    const float* loc  = (const float*)d_in[0];
    const float* cls  = (const float*)d_in[1];
    const float* reg  = (const float*)d_in[2];
    const float* cent = (const float*)d_in[3];
    const int*   imsz = (const int*)d_in[4];
    float* out = (float*)d_out;

    hipLaunchKernelGGL(k0_init,       dim3(625),                 dim3(512),  0, stream, cent);
    hipLaunchKernelGGL(k1_spill,      dim3((M+8191)/8192, NIMG), dim3(512),  0, stream, cls);
    hipLaunchKernelGGL(k2_select_nms, dim3(NIMG),                dim3(1024), 0, stream,
                       cls, loc, reg, imsz, out);
}

// Round 10
// 238.728 us; speedup vs baseline: 1.0765x; 1.0059x over previous
//
#include <hip/hip_runtime.h>
#include <math.h>

#define NIMG 8
#define NCLS 80
#define HW 40000
#define M (NCLS*HW)          // 3,200,000 per image
#define UBINS 4096           // uniform bins over s in [0,1): bin = (int)(s*4096)
#define CANDL 4096           // collect cap (fallback path)
#define SPILL_CAP 65536
#define BCAP 1024
#define TOPK 1000
#define OUTK 100
#define PRE_T 0.05f
#define NMS_T 0.6f
#define FLOOR_BITS 0x3E800000u
#define FLOOR_SAFE 0.2494f

// device-global scratch; counters re-zeroed every call, rest guarded by counts
__device__ unsigned int       g_scnt[NIMG][32];    // padded: 128B per image
__device__ unsigned int       g_ovf[NIMG];
__device__ unsigned int       g_hist[NIMG][UBINS]; // 128 KB: built by k1 (R6)
__device__ unsigned short     g_xthr_b[NIMG * HW]; // R10: bf16 thresholds (640 KB, was 1.25 MB f32)
__device__ float              g_sct[NIMG * HW];    // exact sigmoid(centerness) — stays f32 (exact keys)
__device__ unsigned long long g_key[NIMG][SPILL_CAP];

__device__ __forceinline__ float sigmoid_exact(float x){
    return 1.0f / (1.0f + expf(-x));   // bit-matches ref (absmax 0 across sessions)
}

__device__ __forceinline__ unsigned long long shfl_xor_u64(unsigned long long v, int j){
    int lo = __shfl_xor((int)(unsigned int)(v & 0xffffffffull), j);
    int hi = __shfl_xor((int)(unsigned int)(v >> 32), j);
    return ((unsigned long long)(unsigned int)hi << 32) | (unsigned long long)(unsigned int)lo;
}

// k0: zero counters + g_hist; exact sct table; xthr = logit(FLOOR_SAFE/sct),
// stored as bf16 rounded toward -inf (R10): th_b <= th_f32, so the spill rule
// x >= th_b is a SUPERSET of the proven x >= th_f32 superset of {s >= FLOOR_S}.
// Exactness never depends on the threshold (it only gates exact evaluation);
// only S inflates (~1-3%, absorbed by counters/caps).
__global__ void k0_init(const float* __restrict__ cent){
    int t = blockIdx.x * blockDim.x + threadIdx.x;
    if (t < NIMG * 32) ((unsigned int*)g_scnt)[t] = 0u;
    if (t < NIMG) g_ovf[t] = 0u;
    if (t < NIMG * UBINS) ((unsigned int*)g_hist)[t] = 0u;
    if (t < NIMG * HW){
        float pct = sigmoid_exact(cent[t]);
        g_sct[t] = pct;
        float a = FLOOR_SAFE / pct;
        float xt;
        if (a >= 1.0f) xt = 3.0e38f;   // bf16-truncates to ~2.99e38: still unreachable
        else {
            float am = fminf(a, 0.98f);
            xt = logf(am / (1.0f - am));
        }
        // bf16 encode, round toward -inf: positives truncate (down); negatives
        // bump pattern if any mantissa bits dropped (more negative). xt in
        // [-1.2, +3.9] or sentinel — no overflow/NaN cases.
        unsigned xb = __float_as_uint(xt);
        unsigned hb = xb >> 16;
        if ((xb & 0x80000000u) && (xb & 0xFFFFu)) hb += 1u;
        g_xthr_b[t] = (unsigned short)hb;
    }
}

// k1 (R10): identical spill logic; xthr loads are bf16 (32 B/thread, was 64).
// R9 postmortem model: k1 is MSHR-bound — lines/CU 12.5K x ~750cyc / 64 slots
// = 146K cyc = 61.4us (matches measurement 1%). bf16 xthr cuts lines to 9.4K
// -> predicted ~46-50us. ILP restructures (R7/R8) were neutral: line count is
// the lever, not scheduling. Spill predicate is a superset (see k0) — exact
// keys/hist unchanged in meaning; set may grow ~1-3%.
__global__ void __launch_bounds__(512, 8) k1_spill(const float* __restrict__ cls){
    const int n   = blockIdx.y;
    const int tid = threadIdx.x;
    const int e16 = blockIdx.x * 8192 + tid * 16;  // 16 contiguous elems/thread
    __shared__ unsigned long long skey[BCAP];
    __shared__ unsigned int lcnt, lbase;
    if (tid == 0) lcnt = 0u;
    __syncthreads();

    if (e16 < M){                      // 16|M and e16 16-aligned -> full run valid
        const int c   = e16 / HW;      // 16|HW -> whole run in one class row
        const int hw0 = e16 - c * HW;
        const float* pc = cls + (size_t)n * M + e16;
        const unsigned short* pt = g_xthr_b + n * HW + hw0;   // 32B-aligned (hw0%16==0)
        float4 xa[4];
        uint4  tb[2];
        #pragma unroll
        for (int i = 0; i < 4; ++i) xa[i] = *(const float4*)(pc + i * 4);
        tb[0] = *(const uint4*)(pt);        // bf16 thresholds 0..7
        tb[1] = *(const uint4*)(pt + 8);    // bf16 thresholds 8..15
        float th[16];
        #pragma unroll
        for (int q = 0; q < 2; ++q){
            unsigned w0 = (q?tb[1].x:tb[0].x), w1 = (q?tb[1].y:tb[0].y);
            unsigned w2 = (q?tb[1].z:tb[0].z), w3 = (q?tb[1].w:tb[0].w);
            th[q*8+0] = __uint_as_float((w0 & 0xFFFFu) << 16);
            th[q*8+1] = __uint_as_float((w0 >> 16) << 16);
            th[q*8+2] = __uint_as_float((w1 & 0xFFFFu) << 16);
            th[q*8+3] = __uint_as_float((w1 >> 16) << 16);
            th[q*8+4] = __uint_as_float((w2 & 0xFFFFu) << 16);
            th[q*8+5] = __uint_as_float((w2 >> 16) << 16);
            th[q*8+6] = __uint_as_float((w3 & 0xFFFFu) << 16);
            th[q*8+7] = __uint_as_float((w3 >> 16) << 16);
        }
        #define SPILL1(HWI, XV, THV) \
        if (XV >= THV){ \
            float p_ = sigmoid_exact(XV); \
            if (p_ > PRE_T){ \
                float s_ = p_ * g_sct[n * HW + (HWI)]; \
                unsigned long long key_ = ((unsigned long long)__float_as_uint(s_) << 32) \
                    | (unsigned long long)(0xFFFFFFFFu - (unsigned int)((HWI) * NCLS + c)); \
                atomicAdd(&g_hist[n][(int)(s_ * 4096.0f)], 1u); \
                unsigned int pp_ = atomicAdd(&lcnt, 1u); \
                if (pp_ < BCAP) skey[pp_] = key_; \
            } \
        }
        #pragma unroll
        for (int i = 0; i < 4; ++i){
            SPILL1(hw0 + i*4 + 0, xa[i].x, th[i*4+0])
            SPILL1(hw0 + i*4 + 1, xa[i].y, th[i*4+1])
            SPILL1(hw0 + i*4 + 2, xa[i].z, th[i*4+2])
            SPILL1(hw0 + i*4 + 3, xa[i].w, th[i*4+3])
        }
        #undef SPILL1
    }

    __syncthreads();
    unsigned int raw = lcnt;
    unsigned int cnt = raw < BCAP ? raw : BCAP;
    if (tid == 0){
        lbase = cnt ? atomicAdd(&g_scnt[n][0], cnt) : 0u;
        if (raw > BCAP) g_ovf[n] = 1u;
    }
    __syncthreads();
    unsigned int base = lbase;
    for (unsigned int i = tid; i < cnt; i += 512){
        unsigned int pos = base + i;
        if (pos < SPILL_CAP) g_key[n][pos] = skey[i];
    }
}

struct SelPhase {
    unsigned int hist[UBINS];                 // 16 KB (loaded from g_hist, 4 iters)
    unsigned int cs[256];                     // coarse sums -> IN-PLACE suffix sums
    unsigned int wtot[4];                     // per-wave suffix totals
    unsigned long long keysL[CANDL];          // 32 KB (collect + sort buffer)
};
struct NmsPhase {
    float ox1[TOPK], oy1[TOPK], ox2[TOPK], oy2[TOPK], oar[TOPK];  // offset boxes (fp32 as ref)
    float bxs[TOPK][4];
    float sc[TOPK];
    int   lab[TOPK];
    int   keeplist[OUTK];
    unsigned int  Wc[16][80];     // per-wave per-class counts -> column-exclusive prefixes
    unsigned int  ctot[80];       // class totals (input to parallel prefix)
    unsigned int  coff[81];       // class-exclusive prefix
    unsigned int  wcnt[16];       // keep-compaction wave counts -> prefix
    unsigned short ord[1024];     // class-bucketed candidate ranks (stable in rank)
    unsigned char validf[TOPK];
    unsigned char supp[TOPK];     // used by the serial-NMS fallback only
    unsigned char keepf[1024];
};
union KU { SelPhase sel; NmsPhase nms; };     // ~55 KB (phases don't overlap)

// Register/shfl bitonic steps (region (idx & k)==0 descending; proven R5).
#define REGSTEP(K_, J_) { \
    unsigned long long pa = shfl_xor_u64(va, (J_)); \
    unsigned long long pb = shfl_xor_u64(vb, (J_)); \
    bool fa = ((tid & (J_)) == 0); \
    bool da = ((tid & (K_)) == 0); \
    bool db = (((tid + 1024) & (K_)) == 0); \
    va = (fa == da) ? (va > pa ? va : pa) : (va < pa ? va : pa); \
    vb = (fa == db) ? (vb > pb ? vb : pb) : (vb < pb ? vb : pb); \
}
#define REGSTEP1(K_, J_) { \
    unsigned long long pa = shfl_xor_u64(va, (J_)); \
    bool fa = ((tid & (J_)) == 0); \
    bool da = ((tid & (K_)) == 0); \
    va = (fa == da) ? (va > pa ? va : pa) : (va < pa ? va : pa); \
}

// k2 (R6, unchanged): g_hist load -> parallel cut-find -> collect -> hybrid
// bitonic sized to C (1024/2048) with verify + safety net -> per-class reg NMS.
__global__ void __launch_bounds__(1024) k2_select_nms(const float* __restrict__ cls,
                                                      const float* __restrict__ loc,
                                                      const float* __restrict__ reg,
                                                      const int*   __restrict__ imsz,
                                                      float* __restrict__ out){
    const int n = blockIdx.x;
    const int tid = threadIdx.x;
    const int lane = tid & 63;
    const int wv   = tid >> 6;
    __shared__ KU u;
    __shared__ unsigned long long stop[TOPK];
    __shared__ unsigned int lcnt, s_cut, s_flag, s_nmsfb, s_cnt, s_c, s_csn, s_Cest, s_srtbad;

    for (int i = tid; i < UBINS; i += 1024) u.sel.hist[i] = g_hist[n][i];
    if (tid == 0){ s_nmsfb = 0u; s_srtbad = 0u; s_c = 0xFFFFFFFFu; s_csn = 0u;
                   s_Cest = 0u; s_cut = 0u; lcnt = 0u; }
    if (tid < TOPK) stop[tid] = 0ull;
    __syncthreads();

    unsigned int scnt_raw = g_scnt[n][0];
    unsigned int ovf_f    = g_ovf[n];
    unsigned int S = scnt_raw < SPILL_CAP ? scnt_raw : SPILL_CAP;

    if (tid < 256){
        unsigned int s = 0;
        int base = tid * 16;
        #pragma unroll
        for (int i = 0; i < 16; ++i) s += u.sel.hist[base + i];
        u.sel.cs[tid] = s;
    }
    __syncthreads();
    // in-place inclusive SUFFIX scan of cs[256] (4 waves, shfl_down)
    if (tid < 256){
        unsigned int v = u.sel.cs[tid];
        #pragma unroll
        for (int d = 1; d < 64; d <<= 1){
            unsigned int t = __shfl_down(v, d);
            if (lane + d < 64) v += t;
        }
        if (lane == 0) u.sel.wtot[wv] = v;
        u.sel.cs[tid] = v;
    }
    __syncthreads();
    if (tid < 256){
        unsigned int tail = 0;
        for (int w = wv + 1; w < 4; ++w) tail += u.sel.wtot[w];
        u.sel.cs[tid] += tail;      // cs now holds global suffix sums css[t]
    }
    __syncthreads();
    // coarse crossing: c* = max{t: css[t] >= TOPK}
    if (tid < 256){
        unsigned int a = u.sel.cs[tid];
        unsigned int b = (tid == 255) ? 0u : u.sel.cs[tid + 1];
        if (a >= TOPK && b < TOPK){ s_c = (unsigned int)tid; s_csn = b; }
    }
    __syncthreads();
    // fine crossing within block c* (wave 0, 16-lane suffix scan)
    if (wv == 0 && s_c != 0xFFFFFFFFu){
        unsigned int cst = s_c;
        unsigned int h = (lane < 16) ? u.sel.hist[cst * 16 + lane] : 0u;
        #pragma unroll
        for (int d = 1; d < 16; d <<= 1){
            unsigned int t = __shfl_down(h, d);
            if (lane + d < 16) h += t;
        }
        unsigned int gs  = h + s_csn;            // global suffix at bin cst*16+lane
        unsigned int gsn = __shfl_down(gs, 1);
        if (lane == 15) gsn = s_csn;
        if (lane < 16 && gs >= TOPK && gsn < TOPK){ s_cut = cst * 16 + lane; s_Cest = gs; }
    }
    __syncthreads();
    if (tid == 0){
        unsigned int c025 = u.sel.cs[64];        // suffix at bin 1024 == count{s>=0.25}
        s_flag = (scnt_raw > SPILL_CAP) || ovf_f || (s_c == 0xFFFFFFFFu) ||
                 (c025 < TOPK) || (s_Cest > CANDL) ? 1u : 0u;
    }
    __syncthreads();

    if (s_flag){
        // ---- fallback: exact full rescan (serial cut-find kept verbatim; ~never)
        for (int i = tid; i < UBINS; i += 1024) u.sel.hist[i] = 0u;
        __syncthreads();
        const float* cls_n = cls + (size_t)n * M;
        const float* sct_n = g_sct + n * HW;
        for (int e = tid; e < M; e += 1024){
            float p = sigmoid_exact(cls_n[e]);
            if (p > PRE_T){
                int c = e / HW; int hw = e - c * HW;
                float s = p * sct_n[hw];
                atomicAdd(&u.sel.hist[(int)(s * 4096.0f)], 1u);
            }
        }
        __syncthreads();
        if (tid < 256){
            unsigned int s = 0;
            int base = tid * 16;
            #pragma unroll
            for (int i = 0; i < 16; ++i) s += u.sel.hist[base + i];
            u.sel.cs[tid] = s;
        }
        __syncthreads();
        if (tid == 0){
            unsigned int acc = 0; int cut = 0; int c = 255;
            for (; c >= 0; --c){ if (acc + u.sel.cs[c] >= TOPK) break; acc += u.sel.cs[c]; }
            if (c >= 0){
                int b = c*16 + 15;
                for (;; --b){ acc += u.sel.hist[b]; if (acc >= TOPK || b == c*16) break; }
                cut = b;
            }
            while (acc > CANDL && cut < UBINS){ acc -= u.sel.hist[cut]; cut++; }
            s_cut = (unsigned int)cut;
        }
        __syncthreads();
        unsigned int cutb = s_cut;
        for (int e = tid; e < M; e += 1024){
            float p = sigmoid_exact(cls_n[e]);
            if (p > PRE_T){
                int c = e / HW; int hw = e - c * HW;
                float s = p * sct_n[hw];
                if ((int)(s * 4096.0f) >= (int)cutb){
                    unsigned int pos = atomicAdd(&lcnt, 1u);
                    if (pos < CANDL){
                        unsigned int idx = (unsigned int)(hw * NCLS + c);
                        u.sel.keysL[pos] = ((unsigned long long)__float_as_uint(s) << 32)
                                         | (unsigned long long)(0xFFFFFFFFu - idx);
                    }
                }
            }
        }
    } else {
        // ---- collect keys with bin >= cut (ballot-compacted, proven)
        unsigned int cutb = s_cut;
        for (unsigned int i = tid; i < S; i += 1024){
            unsigned long long k = g_key[n][i];
            float s = __uint_as_float((unsigned int)(k >> 32));
            bool pass = ((unsigned int)(int)(s * 4096.0f)) >= cutb;
            unsigned long long mb = __ballot(pass);
            unsigned int wcnt_ = (unsigned int)__popcll(mb);
            unsigned int base = 0;
            if (lane == 0 && wcnt_) base = atomicAdd(&lcnt, wcnt_);
            base = (unsigned int)__builtin_amdgcn_readfirstlane((int)base);
            if (pass){
                unsigned int p = base + (unsigned int)__popcll(mb & ((1ull << lane) - 1ull));
                if (p < CANDL) u.sel.keysL[p] = k;
            }
        }
    }
    __syncthreads();

    int C = (int)(lcnt < CANDL ? lcnt : CANDL);
    unsigned long long kk = 0ull;
    if (C <= 1024){
        // ---- hybrid bitonic Nsort=1024, 1 elem/thread (typical: Cest ~ 1000-1015)
        for (int i = C + tid; i < 1024; i += 1024) u.sel.keysL[i] = 0ull;
        __syncthreads();
        unsigned long long va = u.sel.keysL[tid];
        REGSTEP1(2,1)
        REGSTEP1(4,2)  REGSTEP1(4,1)
        REGSTEP1(8,4)  REGSTEP1(8,2)  REGSTEP1(8,1)
        REGSTEP1(16,8) REGSTEP1(16,4) REGSTEP1(16,2) REGSTEP1(16,1)
        REGSTEP1(32,16) REGSTEP1(32,8) REGSTEP1(32,4) REGSTEP1(32,2) REGSTEP1(32,1)
        REGSTEP1(64,32) REGSTEP1(64,16) REGSTEP1(64,8) REGSTEP1(64,4) REGSTEP1(64,2) REGSTEP1(64,1)
        for (int k = 128; k <= 1024; k <<= 1){
            u.sel.keysL[tid] = va;
            __syncthreads();
            for (int j = k >> 1; j >= 64; j >>= 1){
                if (tid < 512){
                    int i  = ((tid & ~(j - 1)) << 1) | (tid & (j - 1));
                    int p2 = i | j;
                    unsigned long long a = u.sel.keysL[i];
                    unsigned long long b = u.sel.keysL[p2];
                    bool up = ((i & k) == 0);
                    if (up ? (a < b) : (a > b)){ u.sel.keysL[i] = b; u.sel.keysL[p2] = a; }
                }
                __syncthreads();
            }
            va = u.sel.keysL[tid];
            REGSTEP1(k,32) REGSTEP1(k,16) REGSTEP1(k,8) REGSTEP1(k,4) REGSTEP1(k,2) REGSTEP1(k,1)
        }
        u.sel.keysL[tid] = va;
        __syncthreads();
        // verify descending over [0,1024)
        if (tid <= 1022 && u.sel.keysL[tid] < u.sel.keysL[tid + 1]) atomicOr(&s_srtbad, 1u);
        __syncthreads();
    } else if (C <= 2048){
        // ---- hybrid bitonic Nsort=2048 (R5 proven)
        for (int i = C + tid; i < 2048; i += 1024) u.sel.keysL[i] = 0ull;
        __syncthreads();
        unsigned long long va = u.sel.keysL[tid];
        unsigned long long vb = u.sel.keysL[tid + 1024];
        REGSTEP(2,1)
        REGSTEP(4,2)  REGSTEP(4,1)
        REGSTEP(8,4)  REGSTEP(8,2)  REGSTEP(8,1)
        REGSTEP(16,8) REGSTEP(16,4) REGSTEP(16,2) REGSTEP(16,1)
        REGSTEP(32,16) REGSTEP(32,8) REGSTEP(32,4) REGSTEP(32,2) REGSTEP(32,1)
        REGSTEP(64,32) REGSTEP(64,16) REGSTEP(64,8) REGSTEP(64,4) REGSTEP(64,2) REGSTEP(64,1)
        for (int k = 128; k <= 2048; k <<= 1){
            if (k == 2048){
                unsigned long long mx = va > vb ? va : vb;
                unsigned long long mn = va > vb ? vb : va;
                va = mx; vb = mn;
            }
            u.sel.keysL[tid] = va; u.sel.keysL[tid + 1024] = vb;
            __syncthreads();
            for (int j = (k == 2048) ? 512 : (k >> 1); j >= 64; j >>= 1){
                int i  = ((tid & ~(j - 1)) << 1) | (tid & (j - 1));
                int p2 = i | j;
                unsigned long long a = u.sel.keysL[i];
                unsigned long long b = u.sel.keysL[p2];
                bool up = ((i & k) == 0);
                if (up ? (a < b) : (a > b)){ u.sel.keysL[i] = b; u.sel.keysL[p2] = a; }
                __syncthreads();
            }
            va = u.sel.keysL[tid]; vb = u.sel.keysL[tid + 1024];
            REGSTEP(k,32) REGSTEP(k,16) REGSTEP(k,8) REGSTEP(k,4) REGSTEP(k,2) REGSTEP(k,1)
        }
        u.sel.keysL[tid] = va; u.sel.keysL[tid + 1024] = vb;
        __syncthreads();
        bool bad = (u.sel.keysL[tid] < u.sel.keysL[tid + 1]);
        if (tid <= 1022) bad = bad || (u.sel.keysL[tid + 1024] < u.sel.keysL[tid + 1025]);
        if (bad) atomicOr(&s_srtbad, 1u);
        __syncthreads();
    } else {
        // rare-shape fallback: O(C^2) rank (proven path)
        for (int i = tid; i < C; i += 1024){
            unsigned long long k = u.sel.keysL[i];
            int rank = 0;
            for (int j = 0; j < C; ++j) rank += (u.sel.keysL[j] > k) ? 1 : 0;
            if (rank < TOPK) stop[rank] = k;
        }
        __syncthreads();
        if (tid < TOPK) u.sel.keysL[tid] = stop[tid];   // unify read path
        __syncthreads();
    }

    if (s_srtbad){
        // ---- safety net: re-collect (mode-appropriate) + proven plain bitonic
        if (tid == 0) lcnt = 0u;
        __syncthreads();
        unsigned int cutb = s_cut;
        if (s_flag){
            const float* cls_n = cls + (size_t)n * M;
            const float* sct_n = g_sct + n * HW;
            for (int e = tid; e < M; e += 1024){
                float p = sigmoid_exact(cls_n[e]);
                if (p > PRE_T){
                    int c = e / HW; int hw = e - c * HW;
                    float s = p * sct_n[hw];
                    if ((int)(s * 4096.0f) >= (int)cutb){
                        unsigned int pos = atomicAdd(&lcnt, 1u);
                        if (pos < CANDL){
                            unsigned int idx = (unsigned int)(hw * NCLS + c);
                            u.sel.keysL[pos] = ((unsigned long long)__float_as_uint(s) << 32)
                                             | (unsigned long long)(0xFFFFFFFFu - idx);
                        }
                    }
                }
            }
        } else {
            for (unsigned int i = tid; i < S; i += 1024){
                unsigned long long k = g_key[n][i];
                float s = __uint_as_float((unsigned int)(k >> 32));
                bool pass = ((unsigned int)(int)(s * 4096.0f)) >= cutb;
                unsigned long long mb = __ballot(pass);
                unsigned int wcnt_ = (unsigned int)__popcll(mb);
                unsigned int base = 0;
                if (lane == 0 && wcnt_) base = atomicAdd(&lcnt, wcnt_);
                base = (unsigned int)__builtin_amdgcn_readfirstlane((int)base);
                if (pass){
                    unsigned int p = base + (unsigned int)__popcll(mb & ((1ull << lane) - 1ull));
                    if (p < CANDL) u.sel.keysL[p] = k;
                }
            }
        }
        __syncthreads();
        int C2 = (int)(lcnt < CANDL ? lcnt : CANDL);
        for (int i = C2 + tid; i < 2048; i += 1024) u.sel.keysL[i] = 0ull;
        __syncthreads();
        for (int k = 2; k <= 2048; k <<= 1){
            for (int j = k >> 1; j > 0; j >>= 1){
                int i  = ((tid & ~(j - 1)) << 1) | (tid & (j - 1));
                int p2 = i | j;
                unsigned long long a = u.sel.keysL[i];
                unsigned long long b = u.sel.keysL[p2];
                bool up = ((i & k) == 0);
                if (up ? (a < b) : (a > b)){ u.sel.keysL[i] = b; u.sel.keysL[p2] = a; }
                __syncthreads();
            }
        }
    }
    kk = (tid < TOPK) ? u.sel.keysL[tid] : 0ull;
    __syncthreads();   // fence all sel reads before union reuse writes

    // ---- NMS phase (u.nms aliases u.sel — all sel reads are done)
    float rx1 = 0.f, ry1 = 0.f, rx2 = -1.f, ry2 = -1.f, rar = 1.f;
    float ihh = (float)imsz[2*n + 0];
    float iww = (float)imsz[2*n + 1];

    u.nms.keepf[tid] = 0;
    { unsigned int* wz = &u.nms.Wc[0][0];
      for (int i = tid; i < 16*80; i += 1024) wz[i] = 0u; }

    if (tid < TOPK){
        unsigned int bits = (unsigned int)(kk >> 32);
        float s = __uint_as_float(bits);
        u.nms.supp[tid] = 0;
        if (s > 0.0f){
            unsigned int idx = 0xFFFFFFFFu - (unsigned int)(kk & 0xFFFFFFFFull);
            int hw = (int)(idx / NCLS);
            int c  = (int)(idx % NCLS);
            int l  = c + 1;
            float x  = loc[2*hw], y = loc[2*hw + 1];
            float r0 = reg[((size_t)n*4 + 0)*HW + hw];
            float r1 = reg[((size_t)n*4 + 1)*HW + hw];
            float r2 = reg[((size_t)n*4 + 2)*HW + hw];
            float r3 = reg[((size_t)n*4 + 3)*HW + hw];
            float x1 = fminf(fmaxf(x - r0, 0.0f), iww - 1.0f);
            float y1 = fminf(fmaxf(y - r1, 0.0f), ihh - 1.0f);
            float x2 = fminf(fmaxf(x + r2, 0.0f), iww - 1.0f);
            float y2 = fminf(fmaxf(y + r3, 0.0f), ihh - 1.0f);
            u.nms.bxs[tid][0] = x1; u.nms.bxs[tid][1] = y1;
            u.nms.bxs[tid][2] = x2; u.nms.bxs[tid][3] = y2;
            float off = (float)l * 100000.0f;   // fp32, as reference (quantizes!)
            float a1 = x1 + off, b1 = y1 + off, a2 = x2 + off, b2 = y2 + off;
            float ar = (a2 - a1 + 1.0f) * (b2 - b1 + 1.0f);
            u.nms.ox1[tid] = a1; u.nms.oy1[tid] = b1;
            u.nms.ox2[tid] = a2; u.nms.oy2[tid] = b2; u.nms.oar[tid] = ar;
            rx1 = a1; ry1 = b1; rx2 = a2; ry2 = b2; rar = ar;
            u.nms.sc[tid] = s; u.nms.lab[tid] = l; u.nms.validf[tid] = 1;
        } else {
            u.nms.validf[tid] = 0; u.nms.sc[tid] = 0.0f; u.nms.lab[tid] = 0;
            u.nms.bxs[tid][0] = u.nms.bxs[tid][1] = 0.0f;
            u.nms.bxs[tid][2] = u.nms.bxs[tid][3] = 0.0f;
            u.nms.ox1[tid] = 0.f; u.nms.oy1[tid] = 0.f;
            u.nms.ox2[tid] = -1.f; u.nms.oy2[tid] = -1.f; u.nms.oar[tid] = 1.f;
        }
    }
    __syncthreads();

    // ---- class bucketing (stable in rank): counts -> column prefix -> scatter
    int mk = -1;
    if (tid < TOPK && u.nms.validf[tid]) mk = u.nms.lab[tid] - 1;
    if (mk >= 0) atomicAdd(&u.nms.Wc[wv][mk], 1u);
    __syncthreads();
    if (tid < NCLS){
        unsigned int acc = 0;
        for (int w = 0; w < 16; ++w){
            unsigned int v = u.nms.Wc[w][tid];
            u.nms.Wc[w][tid] = acc;
            acc += v;
        }
        u.nms.ctot[tid] = acc;            // class total
        if (acc > 64) atomicOr(&s_nmsfb, 1u);
    }
    __syncthreads();
    // parallel exclusive prefix over 80 class totals (wave-0 shfl scan)
    if (wv == 0){
        unsigned int v = u.nms.ctot[lane];            // classes 0..63
        unsigned int inc = v;
        #pragma unroll
        for (int d = 1; d < 64; d <<= 1){
            unsigned int t = __shfl_up(inc, d);
            if (lane >= d) inc += t;
        }
        u.nms.coff[lane + 1] = inc;                   // coff[1..64]
        if (lane == 0) u.nms.coff[0] = 0u;
        unsigned int base = __shfl(inc, 63);
        unsigned int inc2 = (lane < 16) ? u.nms.ctot[64 + lane] : 0u;
        #pragma unroll
        for (int d = 1; d < 16; d <<= 1){
            unsigned int t = __shfl_up(inc2, d);
            if (lane >= d) inc2 += t;
        }
        if (lane < 16) u.nms.coff[65 + lane] = base + inc2;   // coff[65..80]
    }
    __syncthreads();

    if (!s_nmsfb){
        // stable within-wave same-class prefix via shfl (register-only)
        int below = 0;
        for (int l = 0; l < 64; ++l){
            int ok = __shfl(mk, l);
            below += (l < lane && ok == mk) ? 1 : 0;
        }
        if (mk >= 0){
            unsigned int pos = u.nms.coff[mk] + u.nms.Wc[wv][mk] + (unsigned int)below;
            u.nms.ord[pos] = (unsigned short)tid;
        }
        __syncthreads();

        // per-class greedy NMS, all in registers (wave w owns classes w, w+16, ...)
        for (int k = wv; k < NCLS; k += 16){
            int base = (int)u.nms.coff[k];
            int ck   = (int)u.nms.coff[k + 1] - base;
            if (ck <= 0) continue;
            int rr = (lane < ck) ? (int)u.nms.ord[base + lane] : -1;
            float bx1 = 0.f, by1 = 0.f, bx2 = -1.f, by2 = -1.f, bar = 1.f;
            if (rr >= 0){
                bx1 = u.nms.ox1[rr]; by1 = u.nms.oy1[rr];
                bx2 = u.nms.ox2[rr]; by2 = u.nms.oy2[rr]; bar = u.nms.oar[rr];
            }
            int sup = 0;
            for (int p = 0; p < ck; ++p){
                int keep_p = !__shfl(sup, p);          // wave-uniform
                if (keep_p){
                    float px1 = __shfl(bx1, p), py1 = __shfl(by1, p);
                    float px2 = __shfl(bx2, p), py2 = __shfl(by2, p);
                    float par = __shfl(bar, p);
                    if (lane > p && rr >= 0){
                        float ix1 = fmaxf(px1, bx1);
                        float iy1 = fmaxf(py1, by1);
                        float ix2 = fminf(px2, bx2);
                        float iy2 = fminf(py2, by2);
                        float iw_ = fmaxf(ix2 - ix1 + 1.0f, 0.0f);
                        float ih_ = fmaxf(iy2 - iy1 + 1.0f, 0.0f);
                        float inter = iw_ * ih_;
                        float iou = inter / (par + bar - inter);
                        if (iou > NMS_T) sup = 1;
                    }
                }
            }
            if (rr >= 0) u.nms.keepf[rr] = sup ? 0 : 1;
        }
        __syncthreads();

        // compact kept candidates in global rank order -> keeplist[0..cnt)
        int kf = (int)u.nms.keepf[tid];
        unsigned long long mb = __ballot(kf != 0);
        if (lane == 0) u.nms.wcnt[wv] = (unsigned int)__popcll(mb);
        __syncthreads();
        if (wv == 0){
            unsigned int v = (lane < 16) ? u.nms.wcnt[lane] : 0u;
            unsigned int orig = v;
            for (int d = 1; d < 16; d <<= 1){
                unsigned int t = __shfl_up(v, d);
                if (lane >= d) v += t;
            }
            if (lane < 16) u.nms.wcnt[lane] = v - orig;   // exclusive
            if (lane == 15) s_cnt = (v < OUTK ? v : OUTK);
        }
        __syncthreads();
        if (kf){
            unsigned int slot = u.nms.wcnt[wv] + (unsigned int)__popcll(mb & ((1ull << lane) - 1ull));
            if (slot < OUTK) u.nms.keeplist[slot] = tid;
        }
    } else {
        // ---- fallback: original serial NMS scan (c_k > 64; ~never on this data)
        int cnt = 0;
        for (int i = 0; i < TOPK; ++i){
            bool keep_i = u.nms.validf[i] && !u.nms.supp[i];
            if (keep_i){
                if (tid == 0) u.nms.keeplist[cnt] = i;
                if (tid < TOPK && tid != i){
                    float ix1 = fmaxf(u.nms.ox1[i], rx1);
                    float iy1 = fmaxf(u.nms.oy1[i], ry1);
                    float ix2 = fminf(u.nms.ox2[i], rx2);
                    float iy2 = fminf(u.nms.oy2[i], ry2);
                    float iw_ = fmaxf(ix2 - ix1 + 1.0f, 0.0f);
                    float ih_ = fmaxf(iy2 - iy1 + 1.0f, 0.0f);
                    float inter = iw_ * ih_;
                    float iou = inter / (u.nms.oar[i] + rar - inter);
                    if (iou > NMS_T) u.nms.supp[tid] = 1;
                }
                cnt++;
                __syncthreads();
                if (cnt == OUTK) break;
            }
        }
        if (tid == 0) s_cnt = (unsigned int)(cnt < OUTK ? cnt : OUTK);
    }
    __syncthreads();

    int cnt = (int)s_cnt;
    if (tid < OUTK){
        float r0=0.f,r1=0.f,r2=0.f,r3=0.f,r4=0.f,r5=0.f;
        if (tid < cnt){
            int i = u.nms.keeplist[tid];
            r0 = u.nms.bxs[i][0]; r1 = u.nms.bxs[i][1];
            r2 = u.nms.bxs[i][2]; r3 = u.nms.bxs[i][3];
            r4 = sqrtf(u.nms.sc[i]); r5 = (float)u.nms.lab[i];
        }
        float* o = out + ((size_t)n*OUTK + tid)*6;
        o[0]=r0; o[1]=r1; o[2]=r2; o[3]=r3; o[4]=r4; o[5]=r5;
    }
}

extern "C" void kernel_launch(void* const* d_in, const int* in_sizes, int n_in,
                              void* d_out, int out_size, void* d_ws, size_t ws_size,
                              hipStream_t stream){
    const float* loc  = (const float*)d_in[0];
    const float* cls  = (const float*)d_in[1];
    const float* reg  = (const float*)d_in[2];
    const float* cent = (const float*)d_in[3];
    const int*   imsz = (const int*)d_in[4];
    float* out = (float*)d_out;

    hipLaunchKernelGGL(k0_init,       dim3(625),                 dim3(512),  0, stream, cent);
    hipLaunchKernelGGL(k1_spill,      dim3((M+8191)/8192, NIMG), dim3(512),  0, stream, cls);
    hipLaunchKernelGGL(k2_select_nms, dim3(NIMG),                dim3(1024), 0, stream,
                       cls, loc, reg, imsz, out);
}